// Round 1
// baseline (3762.582 us; speedup 1.0000x reference)
//
#include <hip/hip_runtime.h>
#include <hip/hip_bf16.h>

#define NN 100000
#define EE 1600000
#define RR 8

__device__ __forceinline__ unsigned short f2bf(float v) {
    __hip_bfloat16 h = __float2bfloat16(v);
    return *reinterpret_cast<unsigned short*>(&h);
}
__device__ __forceinline__ float bf2f(unsigned short u) {
    __hip_bfloat16 h;
    *reinterpret_cast<unsigned short*>(&h) = u;
    return __bfloat162float(h);
}

// m_u encodes float max state for atomicMax: map float -> monotonic uint
__device__ __forceinline__ unsigned fmap(float a) {
    unsigned u = __float_as_uint(a);
    return (u & 0x80000000u) ? ~u : (u | 0x80000000u);
}
__device__ __forceinline__ float funmap(unsigned u) {
    return (u & 0x80000000u) ? __uint_as_float(u & 0x7FFFFFFFu) : __uint_as_float(~u);
}

__global__ __launch_bounds__(256)
void init_softmax_state(unsigned* __restrict__ m_u, float* __restrict__ denom) {
    int i = blockIdx.x * 256 + threadIdx.x;
    if (i < NN) { m_u[i] = 0x007FFFFFu; /* fmap(-inf) */ denom[i] = 0.0f; }
}

// xw[r,n,o] = sum_i x[n,i] * W[r,i,o]; also sq[r,n]=xw·q, sk[r,n]=xw·k
// block: 256 thr = 64 nodes x 64 outs tile, each thread 4 nodes x 4 outs.
template<int IN_DIM, typename T>
__global__ __launch_bounds__(256)
void gemm_xw(const float* __restrict__ x, const float* __restrict__ W,
             const float* __restrict__ qv, const float* __restrict__ kv,
             T* __restrict__ xw, float* __restrict__ sq, float* __restrict__ sk)
{
    __shared__ float Wl[IN_DIM * 64];
    __shared__ float xl[64][68];   // +4 pad: 2-way bank aliasing only (free)
    const int r  = blockIdx.y;
    const int n0 = blockIdx.x * 64;
    const int t  = threadIdx.x;

    {   // stage W[r] (IN_DIM x 64) into LDS
        const float4* Wg = (const float4*)(W + (size_t)r * IN_DIM * 64);
        float4* Wl4 = (float4*)Wl;
        for (int idx = t; idx < IN_DIM * 16; idx += 256) Wl4[idx] = Wg[idx];
    }

    const int og = (t & 15) * 4;   // output quad
    const int ng = (t >> 4) * 4;   // local node quad
    float acc[4][4] = {};

    for (int ib = 0; ib < IN_DIM; ib += 64) {
        // stage 64x64 x-chunk
        for (int idx = t; idx < 64 * 16; idx += 256) {
            int row = idx >> 4, col = (idx & 15) * 4;
            float4 v = make_float4(0.f, 0.f, 0.f, 0.f);
            int gr = n0 + row;
            if (gr < NN) v = *(const float4*)(x + (size_t)gr * IN_DIM + ib + col);
            *(float4*)&xl[row][col] = v;
        }
        __syncthreads();
        for (int i = 0; i < 64; i += 4) {
            float4 wv[4];
            #pragma unroll
            for (int ii = 0; ii < 4; ii++)
                wv[ii] = *(const float4*)&Wl[(ib + i + ii) * 64 + og];
            #pragma unroll
            for (int j = 0; j < 4; j++) {
                float4 xv = *(const float4*)&xl[ng + j][i];
                float xs[4] = {xv.x, xv.y, xv.z, xv.w};
                #pragma unroll
                for (int ii = 0; ii < 4; ii++) {
                    acc[j][0] += xs[ii] * wv[ii].x;
                    acc[j][1] += xs[ii] * wv[ii].y;
                    acc[j][2] += xs[ii] * wv[ii].z;
                    acc[j][3] += xs[ii] * wv[ii].w;
                }
            }
        }
        __syncthreads();
    }

    const float4 qq = *(const float4*)(qv + og);
    const float4 kk = *(const float4*)(kv + og);
    #pragma unroll
    for (int j = 0; j < 4; j++) {
        int gn = n0 + ng + j;
        bool ok = gn < NN;
        if (ok) {
            size_t bidx = ((size_t)r * NN + gn) * 64 + og;
            if constexpr (sizeof(T) == 4) {
                *(float4*)((float*)xw + bidx) =
                    make_float4(acc[j][0], acc[j][1], acc[j][2], acc[j][3]);
            } else {
                ushort4 u;
                u.x = f2bf(acc[j][0]); u.y = f2bf(acc[j][1]);
                u.z = f2bf(acc[j][2]); u.w = f2bf(acc[j][3]);
                *(ushort4*)((unsigned short*)xw + bidx) = u;
            }
        }
        float pq = acc[j][0]*qq.x + acc[j][1]*qq.y + acc[j][2]*qq.z + acc[j][3]*qq.w;
        float pk = acc[j][0]*kk.x + acc[j][1]*kk.y + acc[j][2]*kk.z + acc[j][3]*kk.w;
        #pragma unroll
        for (int m = 8; m >= 1; m >>= 1) {   // reduce across the 16 o-lanes
            pq += __shfl_xor(pq, m, 64);
            pk += __shfl_xor(pk, m, 64);
        }
        if (((t & 15) == 0) && ok) {
            sq[(size_t)r * NN + gn] = pq;
            sk[(size_t)r * NN + gn] = pk;
        }
    }
}

__global__ __launch_bounds__(256)
void edge_scores(const int* __restrict__ src, const int* __restrict__ dst,
                 const int* __restrict__ et,
                 const float* __restrict__ sq, const float* __restrict__ sk,
                 float* __restrict__ alpha, unsigned* __restrict__ m_u)
{
    int e = blockIdx.x * 256 + threadIdx.x;
    if (e >= EE) return;
    int r = et[e], s = src[e], d = dst[e];
    float a = sq[(size_t)r * NN + d] + sk[(size_t)r * NN + s];
    a = a > 0.f ? a : 0.2f * a;          // leaky_relu, negative_slope=0.2
    alpha[e] = a;
    atomicMax(&m_u[d], fmap(a));
}

__global__ __launch_bounds__(256)
void edge_exp(const int* __restrict__ dst, const unsigned* __restrict__ m_u,
              float* __restrict__ alpha, float* __restrict__ denom)
{
    int e = blockIdx.x * 256 + threadIdx.x;
    if (e >= EE) return;
    int d = dst[e];
    float m = funmap(m_u[d]);            // finite: this edge contributed to it
    float ev = __expf(alpha[e] - m);
    alpha[e] = ev;                       // overwrite with exp value
    atomicAdd(&denom[d], ev);
}

template<typename T>
__global__ __launch_bounds__(256)
void edge_aggregate(const int* __restrict__ src, const int* __restrict__ dst,
                    const int* __restrict__ et,
                    const float* __restrict__ ealpha, const float* __restrict__ denom,
                    const T* __restrict__ xw, float* __restrict__ out)
{
    unsigned gid = blockIdx.x * 256 + threadIdx.x;
    unsigned e = gid >> 4;
    if (e >= EE) return;
    int c = (gid & 15) * 4;
    int d = dst[e];
    float a = ealpha[e] / (denom[d] + 1e-16f);
    int s = src[e];
    int r = et[e];
    size_t bidx = ((size_t)r * NN + s) * 64 + c;
    float v0, v1, v2, v3;
    if constexpr (sizeof(T) == 4) {
        float4 v = *(const float4*)((const float*)xw + bidx);
        v0 = v.x; v1 = v.y; v2 = v.z; v3 = v.w;
    } else {
        ushort4 u = *(const ushort4*)((const unsigned short*)xw + bidx);
        v0 = bf2f(u.x); v1 = bf2f(u.y); v2 = bf2f(u.z); v3 = bf2f(u.w);
    }
    float* o = out + (size_t)d * 64 + c;
    atomicAdd(o + 0, v0 * a);
    atomicAdd(o + 1, v1 * a);
    atomicAdd(o + 2, v2 * a);
    atomicAdd(o + 3, v3 * a);
}

__global__ __launch_bounds__(256)
void bias_relu(float* __restrict__ x, const float* __restrict__ b)
{
    int i = blockIdx.x * 256 + threadIdx.x;
    if (i >= NN * 64) return;
    float v = x[i] + b[i & 63];
    x[i] = v > 0.f ? v : 0.f;
}

__global__ __launch_bounds__(256)
void bn_stats(const float* __restrict__ x, float* __restrict__ stats)
{
    int c = threadIdx.x & 63;
    int w = threadIdx.x >> 6;
    float s = 0.f, s2 = 0.f;
    for (int row = blockIdx.x * 4 + w; row < NN; row += gridDim.x * 4) {
        float v = x[(size_t)row * 64 + c];
        s += v; s2 += v * v;
    }
    __shared__ float ls[4][64], ls2[4][64];
    ls[w][c] = s; ls2[w][c] = s2;
    __syncthreads();
    if (threadIdx.x < 64) {
        atomicAdd(&stats[c],      ls[0][c] + ls[1][c] + ls[2][c] + ls[3][c]);
        atomicAdd(&stats[64 + c], ls2[0][c] + ls2[1][c] + ls2[2][c] + ls2[3][c]);
    }
}

__global__ __launch_bounds__(256)
void bn_apply(float* __restrict__ x, const float* __restrict__ stats,
              const float* __restrict__ gamma, const float* __restrict__ beta)
{
    int i = blockIdx.x * 256 + threadIdx.x;
    if (i >= NN * 64) return;
    int c = i & 63;
    float mean = stats[c] * (1.f / NN);
    float var  = stats[64 + c] * (1.f / NN) - mean * mean;
    float sc   = rsqrtf(var + 1e-5f) * gamma[c];
    float v = (x[i] - mean) * sc + beta[c];
    x[i] = v > 0.f ? v : 0.01f * v;      // final leaky_relu 0.01
}

template<typename T>
static void run_all(const float* x0, const int* src, const int* dst, const int* et,
                    const float* W1, const float* q1, const float* k1, const float* b1,
                    const float* W2, const float* q2, const float* k2,
                    const float* gamma, const float* beta,
                    float* out, float* sq, float* sk, float* alpha,
                    unsigned* m_u, float* denom, float* x1, float* stats,
                    T* xw, hipStream_t stream)
{
    const int nb_nodes = (NN + 63) / 64;     // 1563
    const int nb_edges = (EE + 255) / 256;   // 6250
    const int nb_agg   = (EE * 16) / 256;    // 100000
    const int nb_elem  = (NN * 64) / 256;    // 25000
    const int nb_init  = (NN + 255) / 256;

    // ---- layer 1 ----
    hipMemsetAsync(x1, 0, (size_t)NN * 64 * 4, stream);
    init_softmax_state<<<nb_init, 256, 0, stream>>>(m_u, denom);
    gemm_xw<128, T><<<dim3(nb_nodes, RR), 256, 0, stream>>>(x0, W1, q1, k1, xw, sq, sk);
    edge_scores<<<nb_edges, 256, 0, stream>>>(src, dst, et, sq, sk, alpha, m_u);
    edge_exp<<<nb_edges, 256, 0, stream>>>(dst, m_u, alpha, denom);
    edge_aggregate<T><<<nb_agg, 256, 0, stream>>>(src, dst, et, alpha, denom, xw, x1);
    bias_relu<<<nb_elem, 256, 0, stream>>>(x1, b1);

    // ---- layer 2 ----  (b2 is cancelled exactly by BatchNorm mean-subtraction)
    hipMemsetAsync(out, 0, (size_t)NN * 64 * 4, stream);
    hipMemsetAsync(stats, 0, 2 * 64 * 4, stream);
    init_softmax_state<<<nb_init, 256, 0, stream>>>(m_u, denom);
    gemm_xw<64, T><<<dim3(nb_nodes, RR), 256, 0, stream>>>(x1, W2, q2, k2, xw, sq, sk);
    edge_scores<<<nb_edges, 256, 0, stream>>>(src, dst, et, sq, sk, alpha, m_u);
    edge_exp<<<nb_edges, 256, 0, stream>>>(dst, m_u, alpha, denom);
    edge_aggregate<T><<<nb_agg, 256, 0, stream>>>(src, dst, et, alpha, denom, xw, out);

    // ---- batchnorm + leaky_relu ----
    bn_stats<<<256, 256, 0, stream>>>(out, stats);
    bn_apply<<<nb_elem, 256, 0, stream>>>(out, stats, gamma, beta);
}

extern "C" void kernel_launch(void* const* d_in, const int* in_sizes, int n_in,
                              void* d_out, int out_size, void* d_ws, size_t ws_size,
                              hipStream_t stream)
{
    const float* x0 = (const float*)d_in[0];
    const int*   ei = (const int*)d_in[1];
    const int*   et = (const int*)d_in[2];
    const float* W1 = (const float*)d_in[3];
    const float* q1 = (const float*)d_in[4];
    const float* k1 = (const float*)d_in[5];
    const float* b1 = (const float*)d_in[6];
    const float* W2 = (const float*)d_in[7];
    const float* q2 = (const float*)d_in[8];
    const float* k2 = (const float*)d_in[9];
    const float* gamma = (const float*)d_in[11];
    const float* beta  = (const float*)d_in[12];
    const int* src = ei;        // edge_index[0]
    const int* dst = ei + EE;   // edge_index[1]
    float* out = (float*)d_out;

    char* base = (char*)d_ws;
    size_t off = 0;
    auto take = [&](size_t bytes) -> char* {
        char* p = base + off;
        off = (off + bytes + 255) & ~(size_t)255;
        return p;
    };
    float*    sq    = (float*)take((size_t)RR * NN * 4);
    float*    sk    = (float*)take((size_t)RR * NN * 4);
    float*    alpha = (float*)take((size_t)EE * 4);
    unsigned* m_u   = (unsigned*)take((size_t)NN * 4);
    float*    denom = (float*)take((size_t)NN * 4);
    float*    x1    = (float*)take((size_t)NN * 64 * 4);
    float*    stats = (float*)take(512);
    size_t xw_f32_bytes = (size_t)RR * NN * 64 * 4;

    if (ws_size >= off + xw_f32_bytes) {
        float* xw = (float*)take(xw_f32_bytes);
        run_all<float>(x0, src, dst, et, W1, q1, k1, b1, W2, q2, k2, gamma, beta,
                       out, sq, sk, alpha, m_u, denom, x1, stats, xw, stream);
    } else {
        unsigned short* xw = (unsigned short*)take(xw_f32_bytes / 2);
        run_all<unsigned short>(x0, src, dst, et, W1, q1, k1, b1, W2, q2, k2, gamma, beta,
                                out, sq, sk, alpha, m_u, denom, x1, stats, xw, stream);
    }
}

// Round 2
// 1323.963 us; speedup vs baseline: 2.8419x; 2.8419x over previous
//
#include <hip/hip_runtime.h>
#include <hip/hip_bf16.h>

#define NN 100000
#define EE 1600000
#define RR 8
#define SCAN_BS 1024
#define NB_SCAN ((NN + SCAN_BS - 1) / SCAN_BS)   // 98

__device__ __forceinline__ unsigned short f2bf(float v) {
    __hip_bfloat16 h = __float2bfloat16(v);
    return *reinterpret_cast<unsigned short*>(&h);
}
__device__ __forceinline__ float bf2f(unsigned short u) {
    __hip_bfloat16 h;
    *reinterpret_cast<unsigned short*>(&h) = u;
    return __bfloat162float(h);
}

// ---------------- GEMM: xw[r,n,o] = x @ W[r]; sq=xw·q, sk=xw·k ----------------
template<int IN_DIM, typename T>
__global__ __launch_bounds__(256)
void gemm_xw(const float* __restrict__ x, const float* __restrict__ W,
             const float* __restrict__ qv, const float* __restrict__ kv,
             T* __restrict__ xw, float* __restrict__ sq, float* __restrict__ sk)
{
    __shared__ float Wl[IN_DIM * 64];
    __shared__ float xl[64][68];
    const int r  = blockIdx.y;
    const int n0 = blockIdx.x * 64;
    const int t  = threadIdx.x;

    {
        const float4* Wg = (const float4*)(W + (size_t)r * IN_DIM * 64);
        float4* Wl4 = (float4*)Wl;
        for (int idx = t; idx < IN_DIM * 16; idx += 256) Wl4[idx] = Wg[idx];
    }

    const int og = (t & 15) * 4;
    const int ng = (t >> 4) * 4;
    float acc[4][4] = {};

    for (int ib = 0; ib < IN_DIM; ib += 64) {
        for (int idx = t; idx < 64 * 16; idx += 256) {
            int row = idx >> 4, col = (idx & 15) * 4;
            float4 v = make_float4(0.f, 0.f, 0.f, 0.f);
            int gr = n0 + row;
            if (gr < NN) v = *(const float4*)(x + (size_t)gr * IN_DIM + ib + col);
            *(float4*)&xl[row][col] = v;
        }
        __syncthreads();
        for (int i = 0; i < 64; i += 4) {
            float4 wv[4];
            #pragma unroll
            for (int ii = 0; ii < 4; ii++)
                wv[ii] = *(const float4*)&Wl[(ib + i + ii) * 64 + og];
            #pragma unroll
            for (int j = 0; j < 4; j++) {
                float4 xv = *(const float4*)&xl[ng + j][i];
                float xs[4] = {xv.x, xv.y, xv.z, xv.w};
                #pragma unroll
                for (int ii = 0; ii < 4; ii++) {
                    acc[j][0] += xs[ii] * wv[ii].x;
                    acc[j][1] += xs[ii] * wv[ii].y;
                    acc[j][2] += xs[ii] * wv[ii].z;
                    acc[j][3] += xs[ii] * wv[ii].w;
                }
            }
        }
        __syncthreads();
    }

    const float4 qq = *(const float4*)(qv + og);
    const float4 kk = *(const float4*)(kv + og);
    #pragma unroll
    for (int j = 0; j < 4; j++) {
        int gn = n0 + ng + j;
        bool ok = gn < NN;
        if (ok) {
            size_t bidx = ((size_t)r * NN + gn) * 64 + og;
            if constexpr (sizeof(T) == 4) {
                *(float4*)((float*)xw + bidx) =
                    make_float4(acc[j][0], acc[j][1], acc[j][2], acc[j][3]);
            } else {
                ushort4 u;
                u.x = f2bf(acc[j][0]); u.y = f2bf(acc[j][1]);
                u.z = f2bf(acc[j][2]); u.w = f2bf(acc[j][3]);
                *(ushort4*)((unsigned short*)xw + bidx) = u;
            }
        }
        float pq = acc[j][0]*qq.x + acc[j][1]*qq.y + acc[j][2]*qq.z + acc[j][3]*qq.w;
        float pk_ = acc[j][0]*kk.x + acc[j][1]*kk.y + acc[j][2]*kk.z + acc[j][3]*kk.w;
        #pragma unroll
        for (int m = 8; m >= 1; m >>= 1) {
            pq  += __shfl_xor(pq, m, 64);
            pk_ += __shfl_xor(pk_, m, 64);
        }
        if (((t & 15) == 0) && ok) {
            sq[(size_t)r * NN + gn] = pq;
            sk[(size_t)r * NN + gn] = pk_;
        }
    }
}

// ---------------- CSR build (once per call, reused by both layers) ----------------
__global__ __launch_bounds__(256)
void csr_hist(const int* __restrict__ dst, unsigned* __restrict__ cnt) {
    int e = blockIdx.x * 256 + threadIdx.x;
    if (e < EE) atomicAdd(&cnt[dst[e]], 1u);
}

__global__ __launch_bounds__(SCAN_BS)
void scan_block(const unsigned* __restrict__ cnt, unsigned* __restrict__ rowstart,
                unsigned* __restrict__ bsum) {
    __shared__ unsigned sh[SCAN_BS];
    int tid = threadIdx.x;
    int i = blockIdx.x * SCAN_BS + tid;
    unsigned v = (i < NN) ? cnt[i] : 0u;
    sh[tid] = v;
    __syncthreads();
    for (int off = 1; off < SCAN_BS; off <<= 1) {
        unsigned t = (tid >= off) ? sh[tid - off] : 0u;
        __syncthreads();
        sh[tid] += t;
        __syncthreads();
    }
    if (i < NN) rowstart[i] = sh[tid] - v;         // exclusive within block
    if (tid == SCAN_BS - 1) bsum[blockIdx.x] = sh[tid];
}

__global__ void scan_tops(unsigned* __restrict__ bsum) {
    if (threadIdx.x == 0 && blockIdx.x == 0) {
        unsigned run = 0;
        for (int i = 0; i < NB_SCAN; i++) { unsigned t = bsum[i]; bsum[i] = run; run += t; }
    }
}

__global__ __launch_bounds__(256)
void scan_add(unsigned* __restrict__ rowstart, const unsigned* __restrict__ bsum) {
    int i = blockIdx.x * 256 + threadIdx.x;
    if (i < NN) rowstart[i] += bsum[i / SCAN_BS];
    if (i == 0) rowstart[NN] = EE;
}

__global__ __launch_bounds__(256)
void csr_scatter(const int* __restrict__ src, const int* __restrict__ dst,
                 const int* __restrict__ et, const unsigned* __restrict__ rowstart,
                 unsigned* __restrict__ cursor, unsigned* __restrict__ pk) {
    int e = blockIdx.x * 256 + threadIdx.x;
    if (e >= EE) return;
    int d = dst[e];
    unsigned pos = atomicAdd(&cursor[d], 1u);
    pk[rowstart[d] + pos] = ((unsigned)et[e] << 20) | (unsigned)src[e];
}

// ---------------- Fused per-node softmax + aggregate (no atomics) ----------------
// one wave per node; lane = output channel
template<int LAYER, typename T>
__global__ __launch_bounds__(256)
void node_aggregate(const unsigned* __restrict__ rowstart, const unsigned* __restrict__ pk,
                    const float* __restrict__ sq, const float* __restrict__ sk,
                    const T* __restrict__ xw, const float* __restrict__ b,
                    float* __restrict__ out)
{
    int node = blockIdx.x * 4 + (threadIdx.x >> 6);
    int lane = threadIdx.x & 63;
    unsigned beg = rowstart[node], end = rowstart[node + 1];

    float sqv[RR];
    #pragma unroll
    for (int r = 0; r < RR; r++) sqv[r] = sq[(size_t)r * NN + node];

    // pass 1: exact segment max (lane-uniform)
    float m = -1e30f;
    for (unsigned i = beg; i < end; i++) {
        unsigned p = pk[i];
        unsigned r = p >> 20, s = p & 0xFFFFFu;
        float a = sqv[r] + sk[(size_t)r * NN + s];
        a = a > 0.f ? a : 0.2f * a;
        m = fmaxf(m, a);
    }

    // pass 2: exp-weighted gather-accumulate
    float acc0 = 0.f, acc1 = 0.f, den0 = 0.f, den1 = 0.f;
    unsigned i = beg;
    for (; i + 1 < end; i += 2) {
        unsigned p0 = pk[i], p1 = pk[i + 1];
        unsigned r0 = p0 >> 20, s0 = p0 & 0xFFFFFu;
        unsigned r1 = p1 >> 20, s1 = p1 & 0xFFFFFu;
        float a0 = sqv[r0] + sk[(size_t)r0 * NN + s0];
        float a1 = sqv[r1] + sk[(size_t)r1 * NN + s1];
        a0 = a0 > 0.f ? a0 : 0.2f * a0;
        a1 = a1 > 0.f ? a1 : 0.2f * a1;
        float w0 = __expf(a0 - m), w1 = __expf(a1 - m);
        float v0, v1;
        if constexpr (sizeof(T) == 4) {
            v0 = ((const float*)xw)[((size_t)(r0 * NN + s0)) * 64 + lane];
            v1 = ((const float*)xw)[((size_t)(r1 * NN + s1)) * 64 + lane];
        } else {
            v0 = bf2f(((const unsigned short*)xw)[((size_t)(r0 * NN + s0)) * 64 + lane]);
            v1 = bf2f(((const unsigned short*)xw)[((size_t)(r1 * NN + s1)) * 64 + lane]);
        }
        den0 += w0; den1 += w1;
        acc0 += w0 * v0; acc1 += w1 * v1;
    }
    if (i < end) {
        unsigned p = pk[i];
        unsigned r = p >> 20, s = p & 0xFFFFFu;
        float a = sqv[r] + sk[(size_t)r * NN + s];
        a = a > 0.f ? a : 0.2f * a;
        float w = __expf(a - m);
        float v;
        if constexpr (sizeof(T) == 4) {
            v = ((const float*)xw)[((size_t)(r * NN + s)) * 64 + lane];
        } else {
            v = bf2f(((const unsigned short*)xw)[((size_t)(r * NN + s)) * 64 + lane]);
        }
        den0 += w; acc0 += w * v;
    }
    float den = den0 + den1, acc = acc0 + acc1;
    float res = (end > beg) ? acc / (den + 1e-16f) : 0.f;
    if constexpr (LAYER == 1) {
        res += b[lane];
        res = res > 0.f ? res : 0.f;        // relu
    }
    out[(size_t)node * 64 + lane] = res;
}

// ---------------- BatchNorm ----------------
__global__ __launch_bounds__(256)
void bn_stats(const float* __restrict__ x, float* __restrict__ stats)
{
    int c = threadIdx.x & 63;
    int w = threadIdx.x >> 6;
    float s = 0.f, s2 = 0.f;
    for (int row = blockIdx.x * 4 + w; row < NN; row += gridDim.x * 4) {
        float v = x[(size_t)row * 64 + c];
        s += v; s2 += v * v;
    }
    __shared__ float ls[4][64], ls2[4][64];
    ls[w][c] = s; ls2[w][c] = s2;
    __syncthreads();
    if (threadIdx.x < 64) {
        atomicAdd(&stats[c],      ls[0][c] + ls[1][c] + ls[2][c] + ls[3][c]);
        atomicAdd(&stats[64 + c], ls2[0][c] + ls2[1][c] + ls2[2][c] + ls2[3][c]);
    }
}

__global__ __launch_bounds__(256)
void bn_apply(float* __restrict__ x, const float* __restrict__ stats,
              const float* __restrict__ gamma, const float* __restrict__ beta)
{
    int i = blockIdx.x * 256 + threadIdx.x;
    if (i >= NN * 64) return;
    int c = i & 63;
    float mean = stats[c] * (1.f / NN);
    float var  = stats[64 + c] * (1.f / NN) - mean * mean;
    float sc   = rsqrtf(var + 1e-5f) * gamma[c];
    float v = (x[i] - mean) * sc + beta[c];
    x[i] = v > 0.f ? v : 0.01f * v;
}

// ---------------- driver ----------------
template<typename T>
static void run_all(const float* x0, const int* src, const int* dst, const int* et,
                    const float* W1, const float* q1, const float* k1, const float* b1,
                    const float* W2, const float* q2, const float* k2,
                    const float* gamma, const float* beta,
                    float* out, float* sq, float* sk,
                    unsigned* rowstart, unsigned* cnt, unsigned* bsum, unsigned* pk,
                    float* x1, float* stats, T* xw, hipStream_t stream)
{
    const int nb_nodes = (NN + 63) / 64;
    const int nb_edges = (EE + 255) / 256;
    const int nb_agg   = NN / 4;               // 25000 blocks, 4 waves each
    const int nb_elem  = (NN * 64) / 256;
    const int nb_n256  = (NN + 255) / 256;

    // ---- CSR build (shared by both layers) ----
    hipMemsetAsync(cnt, 0, (size_t)NN * 4, stream);
    csr_hist<<<nb_edges, 256, 0, stream>>>(dst, cnt);
    scan_block<<<NB_SCAN, SCAN_BS, 0, stream>>>(cnt, rowstart, bsum);
    scan_tops<<<1, 64, 0, stream>>>(bsum);
    scan_add<<<nb_n256, 256, 0, stream>>>(rowstart, bsum);
    hipMemsetAsync(cnt, 0, (size_t)NN * 4, stream);
    csr_scatter<<<nb_edges, 256, 0, stream>>>(src, dst, et, rowstart, cnt, pk);

    // ---- layer 1 ----
    gemm_xw<128, T><<<dim3(nb_nodes, RR), 256, 0, stream>>>(x0, W1, q1, k1, xw, sq, sk);
    node_aggregate<1, T><<<nb_agg, 256, 0, stream>>>(rowstart, pk, sq, sk, xw, b1, x1);

    // ---- layer 2 ---- (b2 exactly cancelled by BN mean-subtraction; b2==0 anyway)
    gemm_xw<64, T><<<dim3(nb_nodes, RR), 256, 0, stream>>>(x1, W2, q2, k2, xw, sq, sk);
    node_aggregate<2, T><<<nb_agg, 256, 0, stream>>>(rowstart, pk, sq, sk, xw, nullptr, out);

    // ---- batchnorm + leaky_relu ----
    hipMemsetAsync(stats, 0, 2 * 64 * 4, stream);
    bn_stats<<<256, 256, 0, stream>>>(out, stats);
    bn_apply<<<nb_elem, 256, 0, stream>>>(out, stats, gamma, beta);
}

extern "C" void kernel_launch(void* const* d_in, const int* in_sizes, int n_in,
                              void* d_out, int out_size, void* d_ws, size_t ws_size,
                              hipStream_t stream)
{
    const float* x0 = (const float*)d_in[0];
    const int*   ei = (const int*)d_in[1];
    const int*   et = (const int*)d_in[2];
    const float* W1 = (const float*)d_in[3];
    const float* q1 = (const float*)d_in[4];
    const float* k1 = (const float*)d_in[5];
    const float* b1 = (const float*)d_in[6];
    const float* W2 = (const float*)d_in[7];
    const float* q2 = (const float*)d_in[8];
    const float* k2 = (const float*)d_in[9];
    const float* gamma = (const float*)d_in[11];
    const float* beta  = (const float*)d_in[12];
    const int* src = ei;
    const int* dst = ei + EE;
    float* out = (float*)d_out;

    char* base = (char*)d_ws;
    size_t off = 0;
    auto take = [&](size_t bytes) -> char* {
        char* p = base + off;
        off = (off + bytes + 255) & ~(size_t)255;
        return p;
    };
    float*    sq       = (float*)take((size_t)RR * NN * 4);
    float*    sk       = (float*)take((size_t)RR * NN * 4);
    unsigned* rowstart = (unsigned*)take((size_t)(NN + 1) * 4);
    unsigned* cnt      = (unsigned*)take((size_t)NN * 4);
    unsigned* bsum     = (unsigned*)take((size_t)NB_SCAN * 4);
    unsigned* pk       = (unsigned*)take((size_t)EE * 4);
    float*    x1       = (float*)take((size_t)NN * 64 * 4);
    float*    stats    = (float*)take(512);
    size_t xw_f32_bytes = (size_t)RR * NN * 64 * 4;

    if (ws_size >= off + xw_f32_bytes) {
        float* xw = (float*)take(xw_f32_bytes);
        run_all<float>(x0, src, dst, et, W1, q1, k1, b1, W2, q2, k2, gamma, beta,
                       out, sq, sk, rowstart, cnt, bsum, pk, x1, stats, xw, stream);
    } else {
        unsigned short* xw = (unsigned short*)take(xw_f32_bytes / 2);
        run_all<unsigned short>(x0, src, dst, et, W1, q1, k1, b1, W2, q2, k2, gamma, beta,
                                out, sq, sk, rowstart, cnt, bsum, pk, x1, stats, xw, stream);
    }
}

// Round 3
// 949.471 us; speedup vs baseline: 3.9628x; 1.3944x over previous
//
#include <hip/hip_runtime.h>
#include <hip/hip_bf16.h>

#define NN 100000
#define EE 1600000
#define RR 8
#define SCAN_BS 1024
#define NB_SCAN ((NN + SCAN_BS - 1) / SCAN_BS)   // 98

typedef __attribute__((ext_vector_type(8))) short bf16x8;
typedef __attribute__((ext_vector_type(4))) float f32x4;

__device__ __forceinline__ unsigned short f2bf(float v) {
    __hip_bfloat16 h = __float2bfloat16(v);
    return *reinterpret_cast<unsigned short*>(&h);
}
__device__ __forceinline__ float bf2f(unsigned short u) {
    __hip_bfloat16 h;
    *reinterpret_cast<unsigned short*>(&h) = u;
    return __bfloat162float(h);
}

// ---------- W convert+transpose: Wt[r][o][k] = bf16(W[r][k][o]) ----------
template<int IN_DIM>
__global__ __launch_bounds__(256)
void wt_convert(const float* __restrict__ W, unsigned short* __restrict__ Wt) {
    int r = blockIdx.x;
    for (int i = threadIdx.x; i < IN_DIM * 64; i += 256) {
        int k = i >> 6, o = i & 63;
        Wt[((size_t)r * 64 + o) * IN_DIM + k] = f2bf(W[((size_t)r * IN_DIM + k) * 64 + o]);
    }
}

// ---------- MFMA GEMM: xw[r,n,o] bf16 = x @ W[r]; sq=xw·q, sk=xw·k ----------
// block = 256 thr = 4 waves; 64-node tile; loops all 8 relations.
// A-frags loaded once (reused across r). C staged in LDS for coalesced stores.
template<int IN_DIM>
__global__ __launch_bounds__(256)
void gemm_mfma(const float* __restrict__ x, const unsigned short* __restrict__ Wt,
               const float* __restrict__ qv, const float* __restrict__ kv,
               unsigned short* __restrict__ xw,
               float* __restrict__ sq, float* __restrict__ sk)
{
    constexpr int KP = IN_DIM + 8;          // padded LDS row (×2B = multiple of 16B)
    constexpr int KSTEPS = IN_DIM / 32;
    __shared__ unsigned short xl[64 * KP];
    __shared__ unsigned short wl[64 * KP];
    __shared__ unsigned short cst[64 * 72];

    const int n0 = blockIdx.x * 64;
    const int t = threadIdx.x;
    const int wave = t >> 6, lane = t & 63;
    const int quad = lane >> 4, l16 = lane & 15;

    // stage x tile (fp32 -> bf16), coalesced float4 reads
    for (int c = t; c < 64 * IN_DIM / 4; c += 256) {
        int row = c / (IN_DIM / 4), kc = (c % (IN_DIM / 4)) * 4;
        float4 v = make_float4(0.f, 0.f, 0.f, 0.f);
        int gr = n0 + row;
        if (gr < NN) v = *(const float4*)(x + (size_t)gr * IN_DIM + kc);
        ushort4 u;
        u.x = f2bf(v.x); u.y = f2bf(v.y); u.z = f2bf(v.z); u.w = f2bf(v.w);
        *(ushort4*)&xl[row * KP + kc] = u;
    }
    __syncthreads();

    // A-fragments: row m = wave*16 + l16, k = ks*32 + quad*8 .. +7
    bf16x8 afr[KSTEPS];
    #pragma unroll
    for (int ks = 0; ks < KSTEPS; ks++)
        afr[ks] = *(const bf16x8*)&xl[(wave * 16 + l16) * KP + ks * 32 + quad * 8];

    float qvl[4], kvl[4];
    #pragma unroll
    for (int tl = 0; tl < 4; tl++) {
        qvl[tl] = qv[tl * 16 + l16];
        kvl[tl] = kv[tl * 16 + l16];
    }

    for (int r = 0; r < RR; r++) {
        __syncthreads();
        // stage Wt[r] (64 x IN_DIM bf16) into padded LDS
        {
            const unsigned short* Wg = Wt + (size_t)r * 64 * IN_DIM;
            for (int c = t; c < 64 * IN_DIM / 8; c += 256) {
                int o = c / (IN_DIM / 8), kc = (c % (IN_DIM / 8)) * 8;
                *(ushort4*)&wl[o * KP + kc + 0] = *(const ushort4*)(Wg + o * IN_DIM + kc);
                *(ushort4*)&wl[o * KP + kc + 4] = *(const ushort4*)(Wg + o * IN_DIM + kc + 4);
            }
        }
        __syncthreads();

        f32x4 acc[4] = {{0.f,0.f,0.f,0.f},{0.f,0.f,0.f,0.f},{0.f,0.f,0.f,0.f},{0.f,0.f,0.f,0.f}};
        #pragma unroll
        for (int ks = 0; ks < KSTEPS; ks++) {
            #pragma unroll
            for (int tl = 0; tl < 4; tl++) {
                bf16x8 bfr = *(const bf16x8*)&wl[(tl * 16 + l16) * KP + ks * 32 + quad * 8];
                acc[tl] = __builtin_amdgcn_mfma_f32_16x16x32_bf16(afr[ks], bfr, acc[tl], 0, 0, 0);
            }
        }

        // sq/sk: per row n, dot over 64 cols. Lane holds rows quad*4+reg, col tl*16+l16.
        const size_t rbase = (size_t)r * NN;
        #pragma unroll
        for (int reg = 0; reg < 4; reg++) {
            float pq = acc[0][reg]*qvl[0] + acc[1][reg]*qvl[1] + acc[2][reg]*qvl[2] + acc[3][reg]*qvl[3];
            float pk = acc[0][reg]*kvl[0] + acc[1][reg]*kvl[1] + acc[2][reg]*kvl[2] + acc[3][reg]*kvl[3];
            #pragma unroll
            for (int m = 8; m >= 1; m >>= 1) {
                pq += __shfl_xor(pq, m, 64);
                pk += __shfl_xor(pk, m, 64);
            }
            if (l16 == 0) {
                int row = n0 + wave * 16 + quad * 4 + reg;
                if (row < NN) { sq[rbase + row] = pq; sk[rbase + row] = pk; }
            }
        }

        // stage C (bf16) into LDS, then coalesced 16B global stores
        #pragma unroll
        for (int tl = 0; tl < 4; tl++)
            #pragma unroll
            for (int reg = 0; reg < 4; reg++)
                cst[(wave * 16 + quad * 4 + reg) * 72 + tl * 16 + l16] = f2bf(acc[tl][reg]);
        __syncthreads();
        {
            int row = t >> 2, cq = (t & 3) * 16;
            int gr = n0 + row;
            if (gr < NN) {
                unsigned short* dst = xw + (rbase + gr) * 64 + cq;
                *(ushort4*)(dst + 0)  = *(const ushort4*)&cst[row * 72 + cq + 0];
                *(ushort4*)(dst + 4)  = *(const ushort4*)&cst[row * 72 + cq + 4];
                *(ushort4*)(dst + 8)  = *(const ushort4*)&cst[row * 72 + cq + 8];
                *(ushort4*)(dst + 12) = *(const ushort4*)&cst[row * 72 + cq + 12];
            }
        }
    }
}

// ---------------- CSR build ----------------
__global__ __launch_bounds__(256)
void csr_hist(const int* __restrict__ dst, unsigned* __restrict__ cnt) {
    int e = blockIdx.x * 256 + threadIdx.x;
    if (e < EE) atomicAdd(&cnt[dst[e]], 1u);
}

__global__ __launch_bounds__(SCAN_BS)
void scan_block(const unsigned* __restrict__ cnt, unsigned* __restrict__ rowstart,
                unsigned* __restrict__ bsum) {
    __shared__ unsigned sh[SCAN_BS];
    int tid = threadIdx.x;
    int i = blockIdx.x * SCAN_BS + tid;
    unsigned v = (i < NN) ? cnt[i] : 0u;
    sh[tid] = v;
    __syncthreads();
    for (int off = 1; off < SCAN_BS; off <<= 1) {
        unsigned tv = (tid >= off) ? sh[tid - off] : 0u;
        __syncthreads();
        sh[tid] += tv;
        __syncthreads();
    }
    if (i < NN) rowstart[i] = sh[tid] - v;
    if (tid == SCAN_BS - 1) bsum[blockIdx.x] = sh[tid];
}

__global__ void scan_tops(unsigned* __restrict__ bsum) {
    if (threadIdx.x == 0 && blockIdx.x == 0) {
        unsigned run = 0;
        for (int i = 0; i < NB_SCAN; i++) { unsigned t = bsum[i]; bsum[i] = run; run += t; }
    }
}

__global__ __launch_bounds__(256)
void scan_add(unsigned* __restrict__ rowstart, const unsigned* __restrict__ bsum) {
    int i = blockIdx.x * 256 + threadIdx.x;
    if (i < NN) rowstart[i] += bsum[i / SCAN_BS];
    if (i == 0) rowstart[NN] = EE;
}

__global__ __launch_bounds__(256)
void csr_scatter(const int* __restrict__ src, const int* __restrict__ dst,
                 const int* __restrict__ et, const unsigned* __restrict__ rowstart,
                 unsigned* __restrict__ cursor, unsigned* __restrict__ pk) {
    int e = blockIdx.x * 256 + threadIdx.x;
    if (e >= EE) return;
    int d = dst[e];
    unsigned pos = atomicAdd(&cursor[d], 1u);
    pk[rowstart[d] + pos] = ((unsigned)et[e] << 20) | (unsigned)src[e];
}

// ---------- Fused per-node softmax + aggregate (gather, no atomics) ----------
template<int LAYER>
__global__ __launch_bounds__(256)
void node_aggregate(const unsigned* __restrict__ rowstart, const unsigned* __restrict__ pk,
                    const float* __restrict__ sq, const float* __restrict__ sk,
                    const unsigned short* __restrict__ xw, const float* __restrict__ b,
                    float* __restrict__ out)
{
    int node = blockIdx.x * 4 + (threadIdx.x >> 6);
    int lane = threadIdx.x & 63;
    unsigned beg = rowstart[node], end = rowstart[node + 1];

    float sqv[RR];
    #pragma unroll
    for (int r = 0; r < RR; r++) sqv[r] = sq[(size_t)r * NN + node];

    float m = -1e30f;
    for (unsigned i = beg; i < end; i++) {
        unsigned p = pk[i];
        unsigned r = p >> 20, s = p & 0xFFFFFu;
        float a = sqv[r] + sk[(size_t)r * NN + s];
        a = a > 0.f ? a : 0.2f * a;
        m = fmaxf(m, a);
    }

    float acc0 = 0.f, acc1 = 0.f, den0 = 0.f, den1 = 0.f;
    unsigned i = beg;
    for (; i + 1 < end; i += 2) {
        unsigned p0 = pk[i], p1 = pk[i + 1];
        unsigned r0 = p0 >> 20, s0 = p0 & 0xFFFFFu;
        unsigned r1 = p1 >> 20, s1 = p1 & 0xFFFFFu;
        float a0 = sqv[r0] + sk[(size_t)r0 * NN + s0];
        float a1 = sqv[r1] + sk[(size_t)r1 * NN + s1];
        a0 = a0 > 0.f ? a0 : 0.2f * a0;
        a1 = a1 > 0.f ? a1 : 0.2f * a1;
        float w0 = __expf(a0 - m), w1 = __expf(a1 - m);
        float v0 = bf2f(xw[((size_t)(r0 * NN + s0)) * 64 + lane]);
        float v1 = bf2f(xw[((size_t)(r1 * NN + s1)) * 64 + lane]);
        den0 += w0; den1 += w1;
        acc0 += w0 * v0; acc1 += w1 * v1;
    }
    if (i < end) {
        unsigned p = pk[i];
        unsigned r = p >> 20, s = p & 0xFFFFFu;
        float a = sqv[r] + sk[(size_t)r * NN + s];
        a = a > 0.f ? a : 0.2f * a;
        float w = __expf(a - m);
        float v = bf2f(xw[((size_t)(r * NN + s)) * 64 + lane]);
        den0 += w; acc0 += w * v;
    }
    float den = den0 + den1, acc = acc0 + acc1;
    float res = (end > beg) ? acc / (den + 1e-16f) : 0.f;
    if constexpr (LAYER == 1) {
        res += b[lane];
        res = res > 0.f ? res : 0.f;
    }
    out[(size_t)node * 64 + lane] = res;
}

// ---------------- BatchNorm ----------------
__global__ __launch_bounds__(256)
void bn_stats(const float* __restrict__ x, float* __restrict__ stats)
{
    int c = threadIdx.x & 63;
    int w = threadIdx.x >> 6;
    float s = 0.f, s2 = 0.f;
    for (int row = blockIdx.x * 4 + w; row < NN; row += gridDim.x * 4) {
        float v = x[(size_t)row * 64 + c];
        s += v; s2 += v * v;
    }
    __shared__ float ls[4][64], ls2[4][64];
    ls[w][c] = s; ls2[w][c] = s2;
    __syncthreads();
    if (threadIdx.x < 64) {
        atomicAdd(&stats[c],      ls[0][c] + ls[1][c] + ls[2][c] + ls[3][c]);
        atomicAdd(&stats[64 + c], ls2[0][c] + ls2[1][c] + ls2[2][c] + ls2[3][c]);
    }
}

__global__ __launch_bounds__(256)
void bn_apply(float* __restrict__ x, const float* __restrict__ stats,
              const float* __restrict__ gamma, const float* __restrict__ beta)
{
    int i = blockIdx.x * 256 + threadIdx.x;
    if (i >= NN * 64) return;
    int c = i & 63;
    float mean = stats[c] * (1.f / NN);
    float var  = stats[64 + c] * (1.f / NN) - mean * mean;
    float sc   = rsqrtf(var + 1e-5f) * gamma[c];
    float v = (x[i] - mean) * sc + beta[c];
    x[i] = v > 0.f ? v : 0.01f * v;
}

// ---------------- driver ----------------
extern "C" void kernel_launch(void* const* d_in, const int* in_sizes, int n_in,
                              void* d_out, int out_size, void* d_ws, size_t ws_size,
                              hipStream_t stream)
{
    const float* x0 = (const float*)d_in[0];
    const int*   ei = (const int*)d_in[1];
    const int*   et = (const int*)d_in[2];
    const float* W1 = (const float*)d_in[3];
    const float* q1 = (const float*)d_in[4];
    const float* k1 = (const float*)d_in[5];
    const float* b1 = (const float*)d_in[6];
    const float* W2 = (const float*)d_in[7];
    const float* q2 = (const float*)d_in[8];
    const float* k2 = (const float*)d_in[9];
    const float* gamma = (const float*)d_in[11];
    const float* beta  = (const float*)d_in[12];
    const int* src = ei;
    const int* dst = ei + EE;
    float* out = (float*)d_out;

    char* base = (char*)d_ws;
    size_t off = 0;
    auto take = [&](size_t bytes) -> char* {
        char* p = base + off;
        off = (off + bytes + 255) & ~(size_t)255;
        return p;
    };
    float*    sq       = (float*)take((size_t)RR * NN * 4);
    float*    sk       = (float*)take((size_t)RR * NN * 4);
    unsigned* rowstart = (unsigned*)take((size_t)(NN + 1) * 4);
    unsigned* cnt      = (unsigned*)take((size_t)NN * 4);
    unsigned* bsum     = (unsigned*)take((size_t)NB_SCAN * 4);
    unsigned* pk       = (unsigned*)take((size_t)EE * 4);
    float*    x1       = (float*)take((size_t)NN * 64 * 4);
    float*    stats    = (float*)take(512);
    unsigned short* Wt1 = (unsigned short*)take((size_t)RR * 64 * 128 * 2);
    unsigned short* Wt2 = (unsigned short*)take((size_t)RR * 64 * 64 * 2);
    unsigned short* xw  = (unsigned short*)take((size_t)RR * NN * 64 * 2);

    const int nb_nodes = (NN + 63) / 64;       // 1563
    const int nb_edges = (EE + 255) / 256;
    const int nb_agg   = NN / 4;
    const int nb_elem  = (NN * 64) / 256;
    const int nb_n256  = (NN + 255) / 256;

    // ---- weight convert/transpose (tiny) ----
    wt_convert<128><<<RR, 256, 0, stream>>>(W1, Wt1);
    wt_convert<64><<<RR, 256, 0, stream>>>(W2, Wt2);

    // ---- CSR build (shared by both layers) ----
    hipMemsetAsync(cnt, 0, (size_t)NN * 4, stream);
    csr_hist<<<nb_edges, 256, 0, stream>>>(dst, cnt);
    scan_block<<<NB_SCAN, SCAN_BS, 0, stream>>>(cnt, rowstart, bsum);
    scan_tops<<<1, 64, 0, stream>>>(bsum);
    scan_add<<<nb_n256, 256, 0, stream>>>(rowstart, bsum);
    hipMemsetAsync(cnt, 0, (size_t)NN * 4, stream);
    csr_scatter<<<nb_edges, 256, 0, stream>>>(src, dst, et, rowstart, cnt, pk);

    // ---- layer 1 ----
    gemm_mfma<128><<<nb_nodes, 256, 0, stream>>>(x0, Wt1, q1, k1, xw, sq, sk);
    node_aggregate<1><<<nb_agg, 256, 0, stream>>>(rowstart, pk, sq, sk, xw, b1, x1);

    // ---- layer 2 ---- (b2 cancelled exactly by BN mean-subtraction)
    gemm_mfma<64><<<nb_nodes, 256, 0, stream>>>(x1, Wt2, q2, k2, xw, sq, sk);
    node_aggregate<2><<<nb_agg, 256, 0, stream>>>(rowstart, pk, sq, sk, xw, nullptr, out);

    // ---- batchnorm + leaky_relu ----
    hipMemsetAsync(stats, 0, 2 * 64 * 4, stream);
    bn_stats<<<256, 256, 0, stream>>>(out, stats);
    bn_apply<<<nb_elem, 256, 0, stream>>>(out, stats, gamma, beta);
}

// Round 4
// 639.732 us; speedup vs baseline: 5.8815x; 1.4842x over previous
//
#include <hip/hip_runtime.h>
#include <hip/hip_bf16.h>

#define NN 100000
#define EE 1600000
#define RR 8
#define SCAN_BS 1024
#define NB_SCAN ((NN + SCAN_BS - 1) / SCAN_BS)   // 98

typedef __attribute__((ext_vector_type(8))) short bf16x8;
typedef __attribute__((ext_vector_type(4))) float f32x4;

__device__ __forceinline__ unsigned short f2bf(float v) {
    __hip_bfloat16 h = __float2bfloat16(v);
    return *reinterpret_cast<unsigned short*>(&h);
}
__device__ __forceinline__ float bf2f(unsigned short u) {
    unsigned x = (unsigned)u << 16;
    return __uint_as_float(x);
}

// ---------- W convert+transpose: Wt[r][o][k] = bf16(W[r][k][o]) ----------
template<int IN_DIM>
__global__ __launch_bounds__(256)
void wt_convert(const float* __restrict__ W, unsigned short* __restrict__ Wt) {
    int r = blockIdx.x;
    for (int i = threadIdx.x; i < IN_DIM * 64; i += 256) {
        int k = i >> 6, o = i & 63;
        Wt[((size_t)r * 64 + o) * IN_DIM + k] = f2bf(W[((size_t)r * IN_DIM + k) * 64 + o]);
    }
}

// ---------- MFMA GEMM: xw[r,n,o] bf16 = x @ W[r]; sq=xw·q, sk=xw·k ----------
template<int IN_DIM>
__global__ __launch_bounds__(256)
void gemm_mfma(const float* __restrict__ x, const unsigned short* __restrict__ Wt,
               const float* __restrict__ qv, const float* __restrict__ kv,
               unsigned short* __restrict__ xw,
               float* __restrict__ sq, float* __restrict__ sk)
{
    constexpr int KP = IN_DIM + 8;
    constexpr int KSTEPS = IN_DIM / 32;
    __shared__ unsigned short xl[64 * KP];
    __shared__ unsigned short wl[64 * KP];
    __shared__ unsigned short cst[64 * 72];

    const int n0 = blockIdx.x * 64;
    const int t = threadIdx.x;
    const int wave = t >> 6, lane = t & 63;
    const int quad = lane >> 4, l16 = lane & 15;

    for (int c = t; c < 64 * IN_DIM / 4; c += 256) {
        int row = c / (IN_DIM / 4), kc = (c % (IN_DIM / 4)) * 4;
        float4 v = make_float4(0.f, 0.f, 0.f, 0.f);
        int gr = n0 + row;
        if (gr < NN) v = *(const float4*)(x + (size_t)gr * IN_DIM + kc);
        ushort4 u;
        u.x = f2bf(v.x); u.y = f2bf(v.y); u.z = f2bf(v.z); u.w = f2bf(v.w);
        *(ushort4*)&xl[row * KP + kc] = u;
    }
    __syncthreads();

    bf16x8 afr[KSTEPS];
    #pragma unroll
    for (int ks = 0; ks < KSTEPS; ks++)
        afr[ks] = *(const bf16x8*)&xl[(wave * 16 + l16) * KP + ks * 32 + quad * 8];

    float qvl[4], kvl[4];
    #pragma unroll
    for (int tl = 0; tl < 4; tl++) {
        qvl[tl] = qv[tl * 16 + l16];
        kvl[tl] = kv[tl * 16 + l16];
    }

    for (int r = 0; r < RR; r++) {
        __syncthreads();
        {
            const unsigned short* Wg = Wt + (size_t)r * 64 * IN_DIM;
            for (int c = t; c < 64 * IN_DIM / 8; c += 256) {
                int o = c / (IN_DIM / 8), kc = (c % (IN_DIM / 8)) * 8;
                *(ushort4*)&wl[o * KP + kc + 0] = *(const ushort4*)(Wg + o * IN_DIM + kc);
                *(ushort4*)&wl[o * KP + kc + 4] = *(const ushort4*)(Wg + o * IN_DIM + kc + 4);
            }
        }
        __syncthreads();

        f32x4 acc[4] = {{0.f,0.f,0.f,0.f},{0.f,0.f,0.f,0.f},{0.f,0.f,0.f,0.f},{0.f,0.f,0.f,0.f}};
        #pragma unroll
        for (int ks = 0; ks < KSTEPS; ks++) {
            #pragma unroll
            for (int tl = 0; tl < 4; tl++) {
                bf16x8 bfr = *(const bf16x8*)&wl[(tl * 16 + l16) * KP + ks * 32 + quad * 8];
                acc[tl] = __builtin_amdgcn_mfma_f32_16x16x32_bf16(afr[ks], bfr, acc[tl], 0, 0, 0);
            }
        }

        const size_t rbase = (size_t)r * NN;
        #pragma unroll
        for (int reg = 0; reg < 4; reg++) {
            float pq = acc[0][reg]*qvl[0] + acc[1][reg]*qvl[1] + acc[2][reg]*qvl[2] + acc[3][reg]*qvl[3];
            float pk = acc[0][reg]*kvl[0] + acc[1][reg]*kvl[1] + acc[2][reg]*kvl[2] + acc[3][reg]*kvl[3];
            #pragma unroll
            for (int m = 8; m >= 1; m >>= 1) {
                pq += __shfl_xor(pq, m, 64);
                pk += __shfl_xor(pk, m, 64);
            }
            if (l16 == 0) {
                int row = n0 + wave * 16 + quad * 4 + reg;
                if (row < NN) { sq[rbase + row] = pq; sk[rbase + row] = pk; }
            }
        }

        #pragma unroll
        for (int tl = 0; tl < 4; tl++)
            #pragma unroll
            for (int reg = 0; reg < 4; reg++)
                cst[(wave * 16 + quad * 4 + reg) * 72 + tl * 16 + l16] = f2bf(acc[tl][reg]);
        __syncthreads();
        {
            int row = t >> 2, cq = (t & 3) * 16;
            int gr = n0 + row;
            if (gr < NN) {
                unsigned short* dstp = xw + (rbase + gr) * 64 + cq;
                *(ushort4*)(dstp + 0)  = *(const ushort4*)&cst[row * 72 + cq + 0];
                *(ushort4*)(dstp + 4)  = *(const ushort4*)&cst[row * 72 + cq + 4];
                *(ushort4*)(dstp + 8)  = *(const ushort4*)&cst[row * 72 + cq + 8];
                *(ushort4*)(dstp + 12) = *(const ushort4*)&cst[row * 72 + cq + 12];
            }
        }
    }
}

// ---------------- CSR build ----------------
__global__ __launch_bounds__(256)
void csr_hist(const int* __restrict__ dst, unsigned* __restrict__ cnt) {
    int e = blockIdx.x * 256 + threadIdx.x;
    if (e < EE) atomicAdd(&cnt[dst[e]], 1u);
}

__global__ __launch_bounds__(SCAN_BS)
void scan_block(const unsigned* __restrict__ cnt, unsigned* __restrict__ rowstart,
                unsigned* __restrict__ bsum) {
    __shared__ unsigned sh[SCAN_BS];
    int tid = threadIdx.x;
    int i = blockIdx.x * SCAN_BS + tid;
    unsigned v = (i < NN) ? cnt[i] : 0u;
    sh[tid] = v;
    __syncthreads();
    for (int off = 1; off < SCAN_BS; off <<= 1) {
        unsigned tv = (tid >= off) ? sh[tid - off] : 0u;
        __syncthreads();
        sh[tid] += tv;
        __syncthreads();
    }
    if (i < NN) rowstart[i] = sh[tid] - v;
    if (tid == SCAN_BS - 1) bsum[blockIdx.x] = sh[tid];
}

__global__ void scan_tops(unsigned* __restrict__ bsum) {
    if (threadIdx.x == 0 && blockIdx.x == 0) {
        unsigned run = 0;
        for (int i = 0; i < NB_SCAN; i++) { unsigned t = bsum[i]; bsum[i] = run; run += t; }
    }
}

__global__ __launch_bounds__(256)
void scan_add(unsigned* __restrict__ rowstart, const unsigned* __restrict__ bsum) {
    int i = blockIdx.x * 256 + threadIdx.x;
    if (i < NN) rowstart[i] += bsum[i / SCAN_BS];
    if (i == 0) rowstart[NN] = EE;
}

__global__ __launch_bounds__(256)
void csr_scatter(const int* __restrict__ src, const int* __restrict__ dst,
                 const int* __restrict__ et, const unsigned* __restrict__ rowstart,
                 unsigned* __restrict__ cursor, unsigned* __restrict__ pk) {
    int e = blockIdx.x * 256 + threadIdx.x;
    if (e >= EE) return;
    int d = dst[e];
    unsigned pos = atomicAdd(&cursor[d], 1u);
    pk[rowstart[d] + pos] = ((unsigned)et[e] << 20) | (unsigned)src[e];
}

// ---------- Fused per-node softmax + aggregate, v2 ----------
// Phase 1: lane-parallel attention max. Phase 2: per 64-edge chunk, lane
// computes its own w=exp(a-m) (attention math executes ONCE per edge, not
// 64x); inner broadcast loop does the channel-parallel gather with two
// independent acc chains.
template<int LAYER>
__global__ __launch_bounds__(256)
void node_aggregate(const unsigned* __restrict__ rowstart, const unsigned* __restrict__ pk,
                    const float* __restrict__ sq, const float* __restrict__ sk,
                    const unsigned short* __restrict__ xw, const float* __restrict__ b,
                    float* __restrict__ out)
{
    int node = blockIdx.x * 4 + (threadIdx.x >> 6);
    int lane = threadIdx.x & 63;
    unsigned beg = rowstart[node], end = rowstart[node + 1];

    float sqv[RR];
    #pragma unroll
    for (int r = 0; r < RR; r++) sqv[r] = sq[(size_t)r * NN + node];

    // phase 1: lane-parallel segment max
    float m = -1e30f;
    for (unsigned i = beg + lane; i < end; i += 64) {
        unsigned p = pk[i];
        unsigned r = p >> 20;
        unsigned rowidx = r * NN + (p & 0xFFFFFu);
        float a = sqv[r] + sk[rowidx];
        a = a > 0.f ? a : 0.2f * a;
        m = fmaxf(m, a);
    }
    #pragma unroll
    for (int off = 32; off >= 1; off >>= 1)
        m = fmaxf(m, __shfl_xor(m, off, 64));

    // phase 2: chunked exp + broadcast gather
    float acc0 = 0.f, acc1 = 0.f, den = 0.f;
    for (unsigned c0 = beg; c0 < end; c0 += 64) {
        unsigned i = c0 + lane;
        float w = 0.f;
        unsigned rowidx = 0;
        if (i < end) {
            unsigned p = pk[i];
            unsigned r = p >> 20;
            rowidx = r * NN + (p & 0xFFFFFu);
            float a = sqv[r] + sk[rowidx];
            a = a > 0.f ? a : 0.2f * a;
            w = __expf(a - m);
            den += w;
        }
        int cnt = (int)min(64u, end - c0);
        int j = 0;
        for (; j + 1 < cnt; j += 2) {
            float    w0 = __shfl(w, j, 64),            w1 = __shfl(w, j + 1, 64);
            unsigned r0 = (unsigned)__shfl((int)rowidx, j, 64);
            unsigned r1 = (unsigned)__shfl((int)rowidx, j + 1, 64);
            float v0 = bf2f(xw[(size_t)r0 * 64 + lane]);
            float v1 = bf2f(xw[(size_t)r1 * 64 + lane]);
            acc0 += w0 * v0;
            acc1 += w1 * v1;
        }
        if (j < cnt) {
            float    wj = __shfl(w, j, 64);
            unsigned rj = (unsigned)__shfl((int)rowidx, j, 64);
            acc0 += wj * bf2f(xw[(size_t)rj * 64 + lane]);
        }
    }
    #pragma unroll
    for (int off = 32; off >= 1; off >>= 1)
        den += __shfl_xor(den, off, 64);

    float res = (end > beg) ? (acc0 + acc1) / (den + 1e-16f) : 0.f;
    if constexpr (LAYER == 1) {
        res += b[lane];
        res = res > 0.f ? res : 0.f;
    }
    out[(size_t)node * 64 + lane] = res;
}

// ---------------- BatchNorm ----------------
__global__ __launch_bounds__(256)
void bn_stats(const float* __restrict__ x, float* __restrict__ stats)
{
    int c = threadIdx.x & 63;
    int w = threadIdx.x >> 6;
    float s = 0.f, s2 = 0.f;
    for (int row = blockIdx.x * 4 + w; row < NN; row += gridDim.x * 4) {
        float v = x[(size_t)row * 64 + c];
        s += v; s2 += v * v;
    }
    __shared__ float ls[4][64], ls2[4][64];
    ls[w][c] = s; ls2[w][c] = s2;
    __syncthreads();
    if (threadIdx.x < 64) {
        atomicAdd(&stats[c],      ls[0][c] + ls[1][c] + ls[2][c] + ls[3][c]);
        atomicAdd(&stats[64 + c], ls2[0][c] + ls2[1][c] + ls2[2][c] + ls2[3][c]);
    }
}

__global__ __launch_bounds__(256)
void bn_apply(float* __restrict__ x, const float* __restrict__ stats,
              const float* __restrict__ gamma, const float* __restrict__ beta)
{
    int i = blockIdx.x * 256 + threadIdx.x;
    if (i >= NN * 64) return;
    int c = i & 63;
    float mean = stats[c] * (1.f / NN);
    float var  = stats[64 + c] * (1.f / NN) - mean * mean;
    float sc   = rsqrtf(var + 1e-5f) * gamma[c];
    float v = (x[i] - mean) * sc + beta[c];
    x[i] = v > 0.f ? v : 0.01f * v;
}

// ---------------- driver ----------------
extern "C" void kernel_launch(void* const* d_in, const int* in_sizes, int n_in,
                              void* d_out, int out_size, void* d_ws, size_t ws_size,
                              hipStream_t stream)
{
    const float* x0 = (const float*)d_in[0];
    const int*   ei = (const int*)d_in[1];
    const int*   et = (const int*)d_in[2];
    const float* W1 = (const float*)d_in[3];
    const float* q1 = (const float*)d_in[4];
    const float* k1 = (const float*)d_in[5];
    const float* b1 = (const float*)d_in[6];
    const float* W2 = (const float*)d_in[7];
    const float* q2 = (const float*)d_in[8];
    const float* k2 = (const float*)d_in[9];
    const float* gamma = (const float*)d_in[11];
    const float* beta  = (const float*)d_in[12];
    const int* src = ei;
    const int* dst = ei + EE;
    float* out = (float*)d_out;

    char* base = (char*)d_ws;
    size_t off = 0;
    auto take = [&](size_t bytes) -> char* {
        char* p = base + off;
        off = (off + bytes + 255) & ~(size_t)255;
        return p;
    };
    float*    sq       = (float*)take((size_t)RR * NN * 4);
    float*    sk       = (float*)take((size_t)RR * NN * 4);
    unsigned* rowstart = (unsigned*)take((size_t)(NN + 1) * 4);
    unsigned* cnt      = (unsigned*)take((size_t)NN * 4);
    unsigned* bsum     = (unsigned*)take((size_t)NB_SCAN * 4);
    unsigned* pk       = (unsigned*)take((size_t)EE * 4);
    float*    x1       = (float*)take((size_t)NN * 64 * 4);
    float*    stats    = (float*)take(512);
    unsigned short* Wt1 = (unsigned short*)take((size_t)RR * 64 * 128 * 2);
    unsigned short* Wt2 = (unsigned short*)take((size_t)RR * 64 * 64 * 2);
    unsigned short* xw  = (unsigned short*)take((size_t)RR * NN * 64 * 2);

    const int nb_nodes = (NN + 63) / 64;
    const int nb_edges = (EE + 255) / 256;
    const int nb_agg   = NN / 4;
    const int nb_elem  = (NN * 64) / 256;
    const int nb_n256  = (NN + 255) / 256;

    wt_convert<128><<<RR, 256, 0, stream>>>(W1, Wt1);
    wt_convert<64><<<RR, 256, 0, stream>>>(W2, Wt2);

    hipMemsetAsync(cnt, 0, (size_t)NN * 4, stream);
    csr_hist<<<nb_edges, 256, 0, stream>>>(dst, cnt);
    scan_block<<<NB_SCAN, SCAN_BS, 0, stream>>>(cnt, rowstart, bsum);
    scan_tops<<<1, 64, 0, stream>>>(bsum);
    scan_add<<<nb_n256, 256, 0, stream>>>(rowstart, bsum);
    hipMemsetAsync(cnt, 0, (size_t)NN * 4, stream);
    csr_scatter<<<nb_edges, 256, 0, stream>>>(src, dst, et, rowstart, cnt, pk);

    gemm_mfma<128><<<nb_nodes, 256, 0, stream>>>(x0, Wt1, q1, k1, xw, sq, sk);
    node_aggregate<1><<<nb_agg, 256, 0, stream>>>(rowstart, pk, sq, sk, xw, b1, x1);

    gemm_mfma<64><<<nb_nodes, 256, 0, stream>>>(x1, Wt2, q2, k2, xw, sq, sk);
    node_aggregate<2><<<nb_agg, 256, 0, stream>>>(rowstart, pk, sq, sk, xw, nullptr, out);

    hipMemsetAsync(stats, 0, 2 * 64 * 4, stream);
    bn_stats<<<256, 256, 0, stream>>>(out, stats);
    bn_apply<<<nb_elem, 256, 0, stream>>>(out, stats, gamma, beta);
}

// Round 5
// 585.038 us; speedup vs baseline: 6.4313x; 1.0935x over previous
//
#include <hip/hip_runtime.h>
#include <hip/hip_bf16.h>

#define NN 100000
#define EE 1600000
#define RR 8
#define SCAN_BS 1024
#define NB_SCAN ((NN + SCAN_BS - 1) / SCAN_BS)   // 98

typedef __attribute__((ext_vector_type(8))) short bf16x8;
typedef __attribute__((ext_vector_type(4))) float f32x4;

__device__ __forceinline__ unsigned short f2bf(float v) {
    __hip_bfloat16 h = __float2bfloat16(v);
    return *reinterpret_cast<unsigned short*>(&h);
}
__device__ __forceinline__ float bf2f(unsigned short u) {
    unsigned x = (unsigned)u << 16;
    return __uint_as_float(x);
}

// ---------- W -> MFMA B-fragment order ----------
// Wf[(((r*KSTEPS+ks)*4+tl)*64 + lane)*8 + j] = bf16(W[r][k][o])
//   where k = ks*32 + (lane>>4)*8 + j, o = tl*16 + (lane&15)
template<int IN_DIM>
__global__ __launch_bounds__(256)
void wt_frag(const float* __restrict__ W, unsigned short* __restrict__ Wf) {
    constexpr int KSTEPS = IN_DIM / 32;
    int r = blockIdx.x;
    for (int i = threadIdx.x; i < IN_DIM * 64; i += 256) {
        int k = i >> 6, o = i & 63;
        int ks = k >> 5, quad = (k >> 3) & 3, j = k & 7;
        int tl = o >> 4, l16 = o & 15;
        int lane = quad * 16 + l16;
        size_t idx = ((((size_t)r * KSTEPS + ks) * 4 + tl) * 64 + lane) * 8 + j;
        Wf[idx] = f2bf(W[((size_t)r * IN_DIM + k) * 64 + o]);
    }
}

// ---------- MFMA GEMM: xw[r,n,p] bf16 (permuted cols) = x @ W[r]; sq, sk ----------
// xl XOR-swizzled (zero bank conflicts); B-frags from global (L2-resident);
// C stored directly (channel c=tl*16+l16 at row position l16*4+tl).
// Relation loop has NO barriers.
template<int IN_DIM>
__global__ __launch_bounds__(256)
void gemm_mfma(const float* __restrict__ x, const unsigned short* __restrict__ Wf,
               const float* __restrict__ qv, const float* __restrict__ kv,
               unsigned short* __restrict__ xw,
               float* __restrict__ sq, float* __restrict__ sk)
{
    constexpr int KSTEPS = IN_DIM / 32;
    constexpr int NB = IN_DIM / 8;           // 16B blocks per row
    __shared__ unsigned short xl[64 * IN_DIM];

    const int n0 = blockIdx.x * 64;
    const int t = threadIdx.x;
    const int wave = t >> 6, lane = t & 63;
    const int quad = lane >> 4, l16 = lane & 15;

    // stage x tile (fp32 -> bf16), swizzled blocks
    for (int c = t; c < 64 * IN_DIM / 4; c += 256) {
        int row = c / (IN_DIM / 4), kc = (c % (IN_DIM / 4)) * 4;
        float4 v = make_float4(0.f, 0.f, 0.f, 0.f);
        int gr = n0 + row;
        if (gr < NN) v = *(const float4*)(x + (size_t)gr * IN_DIM + kc);
        ushort4 u;
        u.x = f2bf(v.x); u.y = f2bf(v.y); u.z = f2bf(v.z); u.w = f2bf(v.w);
        int b = kc >> 3;
        *(ushort4*)&xl[row * IN_DIM + ((b ^ (row & (NB - 1))) << 3) + (kc & 7)] = u;
    }
    __syncthreads();

    // A-fragments (row = wave*16+l16, swizzled block read)
    bf16x8 afr[KSTEPS];
    const int arow = wave * 16 + l16;
    #pragma unroll
    for (int ks = 0; ks < KSTEPS; ks++) {
        int b = ks * 4 + quad;
        afr[ks] = *(const bf16x8*)&xl[arow * IN_DIM + ((b ^ (arow & (NB - 1))) << 3)];
    }

    float qvl[4], kvl[4];
    #pragma unroll
    for (int tl = 0; tl < 4; tl++) {
        qvl[tl] = qv[tl * 16 + l16];
        kvl[tl] = kv[tl * 16 + l16];
    }

    #pragma unroll 1
    for (int r = 0; r < RR; r++) {
        // B-fragments straight from global (L2-resident, coalesced 16B/lane)
        bf16x8 bfr[KSTEPS][4];
        const unsigned short* Wb = Wf + (((size_t)r * KSTEPS) * 4) * 64 * 8 + lane * 8;
        #pragma unroll
        for (int ks = 0; ks < KSTEPS; ks++)
            #pragma unroll
            for (int tl = 0; tl < 4; tl++)
                bfr[ks][tl] = *(const bf16x8*)(Wb + ((ks * 4 + tl) * 64) * 8);

        f32x4 acc[4] = {{0.f,0.f,0.f,0.f},{0.f,0.f,0.f,0.f},{0.f,0.f,0.f,0.f},{0.f,0.f,0.f,0.f}};
        #pragma unroll
        for (int ks = 0; ks < KSTEPS; ks++)
            #pragma unroll
            for (int tl = 0; tl < 4; tl++)
                acc[tl] = __builtin_amdgcn_mfma_f32_16x16x32_bf16(afr[ks], bfr[ks][tl], acc[tl], 0, 0, 0);

        const size_t rbase = (size_t)r * NN;
        #pragma unroll
        for (int reg = 0; reg < 4; reg++) {
            // sq/sk reduction over the 16 l16 lanes
            float pq = acc[0][reg]*qvl[0] + acc[1][reg]*qvl[1] + acc[2][reg]*qvl[2] + acc[3][reg]*qvl[3];
            float pk = acc[0][reg]*kvl[0] + acc[1][reg]*kvl[1] + acc[2][reg]*kvl[2] + acc[3][reg]*kvl[3];
            #pragma unroll
            for (int m = 8; m >= 1; m >>= 1) {
                pq += __shfl_xor(pq, m, 64);
                pk += __shfl_xor(pk, m, 64);
            }
            int grow = n0 + wave * 16 + quad * 4 + reg;
            if (grow < NN) {
                if (l16 == 0) { sq[rbase + grow] = pq; sk[rbase + grow] = pk; }
                // permuted C store: channel tl*16+l16 -> position l16*4+tl
                ushort4 u;
                u.x = f2bf(acc[0][reg]); u.y = f2bf(acc[1][reg]);
                u.z = f2bf(acc[2][reg]); u.w = f2bf(acc[3][reg]);
                *(ushort4*)(xw + (rbase + grow) * 64 + l16 * 4) = u;
            }
        }
    }
}

// ---------------- CSR build ----------------
__global__ __launch_bounds__(256)
void csr_hist(const int* __restrict__ dst, unsigned* __restrict__ cnt) {
    int e = blockIdx.x * 256 + threadIdx.x;
    if (e < EE) atomicAdd(&cnt[dst[e]], 1u);
}

__global__ __launch_bounds__(SCAN_BS)
void scan_block(const unsigned* __restrict__ cnt, unsigned* __restrict__ rowstart,
                unsigned* __restrict__ bsum) {
    __shared__ unsigned sh[SCAN_BS];
    int tid = threadIdx.x;
    int i = blockIdx.x * SCAN_BS + tid;
    unsigned v = (i < NN) ? cnt[i] : 0u;
    sh[tid] = v;
    __syncthreads();
    for (int off = 1; off < SCAN_BS; off <<= 1) {
        unsigned tv = (tid >= off) ? sh[tid - off] : 0u;
        __syncthreads();
        sh[tid] += tv;
        __syncthreads();
    }
    if (i < NN) rowstart[i] = sh[tid] - v;
    if (tid == SCAN_BS - 1) bsum[blockIdx.x] = sh[tid];
}

__global__ void scan_tops(unsigned* __restrict__ bsum) {
    if (threadIdx.x == 0 && blockIdx.x == 0) {
        unsigned run = 0;
        for (int i = 0; i < NB_SCAN; i++) { unsigned t = bsum[i]; bsum[i] = run; run += t; }
    }
}

__global__ __launch_bounds__(256)
void scan_add(unsigned* __restrict__ rowstart, const unsigned* __restrict__ bsum) {
    int i = blockIdx.x * 256 + threadIdx.x;
    if (i < NN) rowstart[i] += bsum[i / SCAN_BS];
    if (i == 0) rowstart[NN] = EE;
}

__global__ __launch_bounds__(256)
void csr_scatter(const int* __restrict__ src, const int* __restrict__ dst,
                 const int* __restrict__ et, const unsigned* __restrict__ rowstart,
                 unsigned* __restrict__ cursor, unsigned* __restrict__ pk) {
    int e = blockIdx.x * 256 + threadIdx.x;
    if (e >= EE) return;
    int d = dst[e];
    unsigned pos = atomicAdd(&cursor[d], 1u);
    pk[rowstart[d] + pos] = ((unsigned)et[e] << 20) | (unsigned)src[e];
}

// ---------- Fused per-node softmax + aggregate ----------
// lane's xw position = lane; its true channel = (lane&3)*16 + (lane>>2)
template<int LAYER>
__global__ __launch_bounds__(256)
void node_aggregate(const unsigned* __restrict__ rowstart, const unsigned* __restrict__ pk,
                    const float* __restrict__ sq, const float* __restrict__ sk,
                    const unsigned short* __restrict__ xw, const float* __restrict__ b,
                    float* __restrict__ out)
{
    int node = blockIdx.x * 4 + (threadIdx.x >> 6);
    int lane = threadIdx.x & 63;
    int c_lane = ((lane & 3) << 4) | (lane >> 2);
    unsigned beg = rowstart[node], end = rowstart[node + 1];

    float sqv[RR];
    #pragma unroll
    for (int r = 0; r < RR; r++) sqv[r] = sq[(size_t)r * NN + node];

    // phase 1: lane-parallel segment max
    float m = -1e30f;
    for (unsigned i = beg + lane; i < end; i += 64) {
        unsigned p = pk[i];
        unsigned r = p >> 20;
        unsigned rowidx = r * NN + (p & 0xFFFFFu);
        float a = sqv[r] + sk[rowidx];
        a = a > 0.f ? a : 0.2f * a;
        m = fmaxf(m, a);
    }
    #pragma unroll
    for (int off = 32; off >= 1; off >>= 1)
        m = fmaxf(m, __shfl_xor(m, off, 64));

    // phase 2: chunked exp + broadcast gather
    float acc0 = 0.f, acc1 = 0.f, den = 0.f;
    for (unsigned c0 = beg; c0 < end; c0 += 64) {
        unsigned i = c0 + lane;
        float w = 0.f;
        unsigned rowidx = 0;
        if (i < end) {
            unsigned p = pk[i];
            unsigned r = p >> 20;
            rowidx = r * NN + (p & 0xFFFFFu);
            float a = sqv[r] + sk[rowidx];
            a = a > 0.f ? a : 0.2f * a;
            w = __expf(a - m);
            den += w;
        }
        int cnt = (int)min(64u, end - c0);
        int j = 0;
        for (; j + 1 < cnt; j += 2) {
            float    w0 = __shfl(w, j, 64),            w1 = __shfl(w, j + 1, 64);
            unsigned r0 = (unsigned)__shfl((int)rowidx, j, 64);
            unsigned r1 = (unsigned)__shfl((int)rowidx, j + 1, 64);
            float v0 = bf2f(xw[(size_t)r0 * 64 + lane]);
            float v1 = bf2f(xw[(size_t)r1 * 64 + lane]);
            acc0 += w0 * v0;
            acc1 += w1 * v1;
        }
        if (j < cnt) {
            float    wj = __shfl(w, j, 64);
            unsigned rj = (unsigned)__shfl((int)rowidx, j, 64);
            acc0 += wj * bf2f(xw[(size_t)rj * 64 + lane]);
        }
    }
    #pragma unroll
    for (int off = 32; off >= 1; off >>= 1)
        den += __shfl_xor(den, off, 64);

    float res = (end > beg) ? (acc0 + acc1) / (den + 1e-16f) : 0.f;
    if constexpr (LAYER == 1) {
        res += b[c_lane];
        res = res > 0.f ? res : 0.f;
    }
    out[(size_t)node * 64 + c_lane] = res;
}

// ---------------- BatchNorm ----------------
__global__ __launch_bounds__(256)
void bn_stats(const float* __restrict__ x, float* __restrict__ stats)
{
    int c = threadIdx.x & 63;
    int w = threadIdx.x >> 6;
    float s = 0.f, s2 = 0.f;
    for (int row = blockIdx.x * 4 + w; row < NN; row += gridDim.x * 4) {
        float v = x[(size_t)row * 64 + c];
        s += v; s2 += v * v;
    }
    __shared__ float ls[4][64], ls2[4][64];
    ls[w][c] = s; ls2[w][c] = s2;
    __syncthreads();
    if (threadIdx.x < 64) {
        atomicAdd(&stats[c],      ls[0][c] + ls[1][c] + ls[2][c] + ls[3][c]);
        atomicAdd(&stats[64 + c], ls2[0][c] + ls2[1][c] + ls2[2][c] + ls2[3][c]);
    }
}

__global__ __launch_bounds__(256)
void bn_apply(float* __restrict__ x, const float* __restrict__ stats,
              const float* __restrict__ gamma, const float* __restrict__ beta)
{
    int i = blockIdx.x * 256 + threadIdx.x;
    if (i >= NN * 64) return;
    int c = i & 63;
    float mean = stats[c] * (1.f / NN);
    float var  = stats[64 + c] * (1.f / NN) - mean * mean;
    float sc   = rsqrtf(var + 1e-5f) * gamma[c];
    float v = (x[i] - mean) * sc + beta[c];
    x[i] = v > 0.f ? v : 0.01f * v;
}

// ---------------- driver ----------------
extern "C" void kernel_launch(void* const* d_in, const int* in_sizes, int n_in,
                              void* d_out, int out_size, void* d_ws, size_t ws_size,
                              hipStream_t stream)
{
    const float* x0 = (const float*)d_in[0];
    const int*   ei = (const int*)d_in[1];
    const int*   et = (const int*)d_in[2];
    const float* W1 = (const float*)d_in[3];
    const float* q1 = (const float*)d_in[4];
    const float* k1 = (const float*)d_in[5];
    const float* b1 = (const float*)d_in[6];
    const float* W2 = (const float*)d_in[7];
    const float* q2 = (const float*)d_in[8];
    const float* k2 = (const float*)d_in[9];
    const float* gamma = (const float*)d_in[11];
    const float* beta  = (const float*)d_in[12];
    const int* src = ei;
    const int* dst = ei + EE;
    float* out = (float*)d_out;

    char* base = (char*)d_ws;
    size_t off = 0;
    auto take = [&](size_t bytes) -> char* {
        char* p = base + off;
        off = (off + bytes + 255) & ~(size_t)255;
        return p;
    };
    float*    sq       = (float*)take((size_t)RR * NN * 4);
    float*    sk       = (float*)take((size_t)RR * NN * 4);
    unsigned* rowstart = (unsigned*)take((size_t)(NN + 1) * 4);
    unsigned* cnt      = (unsigned*)take((size_t)NN * 4);
    unsigned* bsum     = (unsigned*)take((size_t)NB_SCAN * 4);
    unsigned* pk       = (unsigned*)take((size_t)EE * 4);
    float*    x1       = (float*)take((size_t)NN * 64 * 4);
    float*    stats    = (float*)take(512);
    unsigned short* Wf1 = (unsigned short*)take((size_t)RR * 64 * 128 * 2);
    unsigned short* Wf2 = (unsigned short*)take((size_t)RR * 64 * 64 * 2);
    unsigned short* xw  = (unsigned short*)take((size_t)RR * NN * 64 * 2);

    const int nb_nodes = (NN + 63) / 64;
    const int nb_edges = (EE + 255) / 256;
    const int nb_agg   = NN / 4;
    const int nb_elem  = (NN * 64) / 256;
    const int nb_n256  = (NN + 255) / 256;

    wt_frag<128><<<RR, 256, 0, stream>>>(W1, Wf1);
    wt_frag<64><<<RR, 256, 0, stream>>>(W2, Wf2);

    hipMemsetAsync(cnt, 0, (size_t)NN * 4, stream);
    csr_hist<<<nb_edges, 256, 0, stream>>>(dst, cnt);
    scan_block<<<NB_SCAN, SCAN_BS, 0, stream>>>(cnt, rowstart, bsum);
    scan_tops<<<1, 64, 0, stream>>>(bsum);
    scan_add<<<nb_n256, 256, 0, stream>>>(rowstart, bsum);
    hipMemsetAsync(cnt, 0, (size_t)NN * 4, stream);
    csr_scatter<<<nb_edges, 256, 0, stream>>>(src, dst, et, rowstart, cnt, pk);

    gemm_mfma<128><<<nb_nodes, 256, 0, stream>>>(x0, Wf1, q1, k1, xw, sq, sk);
    node_aggregate<1><<<nb_agg, 256, 0, stream>>>(rowstart, pk, sq, sk, xw, b1, x1);

    gemm_mfma<64><<<nb_nodes, 256, 0, stream>>>(x1, Wf2, q2, k2, xw, sq, sk);
    node_aggregate<2><<<nb_agg, 256, 0, stream>>>(rowstart, pk, sq, sk, xw, nullptr, out);

    hipMemsetAsync(stats, 0, 2 * 64 * 4, stream);
    bn_stats<<<256, 256, 0, stream>>>(out, stats);
    bn_apply<<<nb_elem, 256, 0, stream>>>(out, stats, gamma, beta);
}

// Round 8
// 564.430 us; speedup vs baseline: 6.6662x; 1.0365x over previous
//
#include <hip/hip_runtime.h>
#include <hip/hip_bf16.h>

#define NN 100000
#define EE 1600000
#define RR 8
#define SCAN_BS 1024
#define NB_SCAN ((NN + SCAN_BS - 1) / SCAN_BS)   // 98

typedef __attribute__((ext_vector_type(8))) short bf16x8;
typedef __attribute__((ext_vector_type(4))) float f32x4;

__device__ __forceinline__ unsigned short f2bf(float v) {
    __hip_bfloat16 h = __float2bfloat16(v);
    return *reinterpret_cast<unsigned short*>(&h);
}
__device__ __forceinline__ float bf2f(unsigned short u) {
    unsigned x = (unsigned)u << 16;
    return __uint_as_float(x);
}
__device__ __forceinline__ unsigned fmap(float a) {
    unsigned u = __float_as_uint(a);
    return (u & 0x80000000u) ? ~u : (u | 0x80000000u);
}
__device__ __forceinline__ float funmap(unsigned u) {
    return (u & 0x80000000u) ? __uint_as_float(u & 0x7FFFFFFFu) : __uint_as_float(~u);
}

// ---------- W -> MFMA B-fragment order ----------
template<int IN_DIM>
__global__ __launch_bounds__(256)
void wt_frag(const float* __restrict__ W, unsigned short* __restrict__ Wf) {
    constexpr int KSTEPS = IN_DIM / 32;
    int r = blockIdx.x;
    for (int i = threadIdx.x; i < IN_DIM * 64; i += 256) {
        int k = i >> 6, o = i & 63;
        int ks = k >> 5, quad = (k >> 3) & 3, j = k & 7;
        int tl = o >> 4, l16 = o & 15;
        int lane = quad * 16 + l16;
        size_t idx = ((((size_t)r * KSTEPS + ks) * 4 + tl) * 64 + lane) * 8 + j;
        Wf[idx] = f2bf(W[((size_t)r * IN_DIM + k) * 64 + o]);
    }
}

// ---------- packed score B-frag: col<8 -> W[col]@q, col>=8 -> W[col-8]@k ----------
template<int IN_DIM>
__global__ __launch_bounds__(256)
void wqk_frag(const float* __restrict__ W, const float* __restrict__ q,
              const float* __restrict__ k, unsigned short* __restrict__ Sf) {
    for (int i = blockIdx.x * 256 + threadIdx.x; i < IN_DIM * 16; i += gridDim.x * 256) {
        int j = i & 7, lane = (i >> 3) & 63, ks = i >> 9;
        int col = lane & 15, quad = lane >> 4;
        int kd = ks * 32 + quad * 8 + j;
        const float* v = (col < 8) ? q : k;
        int r = (col < 8) ? col : col - 8;
        float s = 0.f;
        #pragma unroll
        for (int o = 0; o < 64; o++) s += W[((size_t)r * IN_DIM + kd) * 64 + o] * v[o];
        Sf[i] = f2bf(s);
    }
}

__global__ void init_mxk16(unsigned* __restrict__ a, unsigned* __restrict__ b) {
    if (threadIdx.x < RR) { a[threadIdx.x] = fmap(-1e30f); b[threadIdx.x] = fmap(-1e30f); }
}

// per-relation max of sk (grid (RR, 8), block 256)
__global__ __launch_bounds__(256)
void sk_max(const float* __restrict__ sk, unsigned* __restrict__ mxk_u) {
    int r = blockIdx.x;
    int t = threadIdx.x;
    float m = -1e30f;
    for (int i = blockIdx.y * (NN / 8) + t; i < (blockIdx.y + 1) * (NN / 8); i += 256)
        m = fmaxf(m, sk[(size_t)r * NN + i]);
    #pragma unroll
    for (int off = 32; off >= 1; off >>= 1)
        m = fmaxf(m, __shfl_xor(m, off, 64));
    __shared__ float sm[4];
    if ((t & 63) == 0) sm[t >> 6] = m;
    __syncthreads();
    if (t == 0) {
        m = fmaxf(fmaxf(sm[0], sm[1]), fmaxf(sm[2], sm[3]));
        atomicMax(&mxk_u[r], fmap(m));
    }
}

// ---------- MFMA GEMM: xw[r,n,p] bf16 (permuted cols) = x @ W[r]; sq/sk via MFMA ----------
template<int IN_DIM>
__global__ __launch_bounds__(256)
void gemm_mfma(const float* __restrict__ x, const unsigned short* __restrict__ Wf,
               const unsigned short* __restrict__ Sf,
               unsigned short* __restrict__ xw,
               float* __restrict__ sq, float* __restrict__ sk)
{
    constexpr int KSTEPS = IN_DIM / 32;
    constexpr int NB = IN_DIM / 8;
    __shared__ unsigned short xl[64 * IN_DIM];

    const int n0 = blockIdx.x * 64;
    const int t = threadIdx.x;
    const int wave = t >> 6, lane = t & 63;
    const int quad = lane >> 4, l16 = lane & 15;

    for (int c = t; c < 64 * IN_DIM / 4; c += 256) {
        int row = c / (IN_DIM / 4), kc = (c % (IN_DIM / 4)) * 4;
        float4 v = make_float4(0.f, 0.f, 0.f, 0.f);
        int gr = n0 + row;
        if (gr < NN) v = *(const float4*)(x + (size_t)gr * IN_DIM + kc);
        ushort4 u;
        u.x = f2bf(v.x); u.y = f2bf(v.y); u.z = f2bf(v.z); u.w = f2bf(v.w);
        int b = kc >> 3;
        *(ushort4*)&xl[row * IN_DIM + ((b ^ (row & (NB - 1))) << 3) + (kc & 7)] = u;
    }
    __syncthreads();

    bf16x8 afr[KSTEPS];
    const int arow = wave * 16 + l16;
    #pragma unroll
    for (int ks = 0; ks < KSTEPS; ks++) {
        int b = ks * 4 + quad;
        afr[ks] = *(const bf16x8*)&xl[arow * IN_DIM + ((b ^ (arow & (NB - 1))) << 3)];
    }

    // ---- sq/sk for ALL relations via one MFMA chain ----
    {
        f32x4 accs = {0.f, 0.f, 0.f, 0.f};
        #pragma unroll
        for (int ks = 0; ks < KSTEPS; ks++) {
            bf16x8 sfr = *(const bf16x8*)&Sf[(ks * 64 + lane) * 8];
            accs = __builtin_amdgcn_mfma_f32_16x16x32_bf16(afr[ks], sfr, accs, 0, 0, 0);
        }
        #pragma unroll
        for (int reg = 0; reg < 4; reg++) {
            int grow = n0 + wave * 16 + quad * 4 + reg;
            if (grow < NN) {
                if (l16 < 8) sq[(size_t)l16 * NN + grow] = accs[reg];
                else         sk[(size_t)(l16 - 8) * NN + grow] = accs[reg];
            }
        }
    }

    #pragma unroll 1
    for (int r = 0; r < RR; r++) {
        bf16x8 bfr[KSTEPS][4];
        const unsigned short* Wb = Wf + (((size_t)r * KSTEPS) * 4) * 64 * 8 + lane * 8;
        #pragma unroll
        for (int ks = 0; ks < KSTEPS; ks++)
            #pragma unroll
            for (int tl = 0; tl < 4; tl++)
                bfr[ks][tl] = *(const bf16x8*)(Wb + ((ks * 4 + tl) * 64) * 8);

        f32x4 acc[4] = {{0.f,0.f,0.f,0.f},{0.f,0.f,0.f,0.f},{0.f,0.f,0.f,0.f},{0.f,0.f,0.f,0.f}};
        #pragma unroll
        for (int ks = 0; ks < KSTEPS; ks++)
            #pragma unroll
            for (int tl = 0; tl < 4; tl++)
                acc[tl] = __builtin_amdgcn_mfma_f32_16x16x32_bf16(afr[ks], bfr[ks][tl], acc[tl], 0, 0, 0);

        const size_t rbase = (size_t)r * NN;
        #pragma unroll
        for (int reg = 0; reg < 4; reg++) {
            int grow = n0 + wave * 16 + quad * 4 + reg;
            if (grow < NN) {
                ushort4 u;
                u.x = f2bf(acc[0][reg]); u.y = f2bf(acc[1][reg]);
                u.z = f2bf(acc[2][reg]); u.w = f2bf(acc[3][reg]);
                *(ushort4*)(xw + (rbase + grow) * 64 + l16 * 4) = u;
            }
        }
    }
}

// ---------------- CSR build ----------------
__global__ __launch_bounds__(256)
void csr_hist(const int* __restrict__ dst, unsigned* __restrict__ cnt) {
    int e = blockIdx.x * 256 + threadIdx.x;
    if (e < EE) atomicAdd(&cnt[dst[e]], 1u);
}

__global__ __launch_bounds__(SCAN_BS)
void scan_block(const unsigned* __restrict__ cnt, unsigned* __restrict__ rowstart,
                unsigned* __restrict__ bsum) {
    __shared__ unsigned sh[SCAN_BS];
    int tid = threadIdx.x;
    int i = blockIdx.x * SCAN_BS + tid;
    unsigned v = (i < NN) ? cnt[i] : 0u;
    sh[tid] = v;
    __syncthreads();
    for (int off = 1; off < SCAN_BS; off <<= 1) {
        unsigned tv = (tid >= off) ? sh[tid - off] : 0u;
        __syncthreads();
        sh[tid] += tv;
        __syncthreads();
    }
    if (i < NN) rowstart[i] = sh[tid] - v;
    if (tid == SCAN_BS - 1) bsum[blockIdx.x] = sh[tid];
}

__global__ void scan_tops(unsigned* __restrict__ bsum) {
    if (threadIdx.x == 0 && blockIdx.x == 0) {
        unsigned run = 0;
        for (int i = 0; i < NB_SCAN; i++) { unsigned t = bsum[i]; bsum[i] = run; run += t; }
    }
}

__global__ __launch_bounds__(256)
void scan_add(unsigned* __restrict__ rowstart, const unsigned* __restrict__ bsum) {
    int i = blockIdx.x * 256 + threadIdx.x;
    if (i < NN) rowstart[i] += bsum[i / SCAN_BS];
    if (i == 0) rowstart[NN] = EE;
}

__global__ __launch_bounds__(256)
void csr_scatter(const int* __restrict__ src, const int* __restrict__ dst,
                 const int* __restrict__ et, const unsigned* __restrict__ rowstart,
                 unsigned* __restrict__ cursor, unsigned* __restrict__ pk) {
    int e = blockIdx.x * 256 + threadIdx.x;
    if (e >= EE) return;
    int d = dst[e];
    unsigned pos = atomicAdd(&cursor[d], 1u);
    pk[rowstart[d] + pos] = ((unsigned)et[e] << 20) | (unsigned)src[e];
}

// ---------- Fused per-node softmax + aggregate ----------
// Upper-bound max (no per-edge max pass): m = leaky(max_r(sq[r,node]+mxk[r])).
// lane's xw position = lane; its true channel = (lane&3)*16 + (lane>>2)
template<int LAYER>
__global__ __launch_bounds__(256)
void node_aggregate(const unsigned* __restrict__ rowstart, const unsigned* __restrict__ pk,
                    const float* __restrict__ sq, const float* __restrict__ sk,
                    const unsigned* __restrict__ mxk_u,
                    const unsigned short* __restrict__ xw, const float* __restrict__ b,
                    float* __restrict__ out)
{
    int node = blockIdx.x * 4 + (threadIdx.x >> 6);
    int lane = threadIdx.x & 63;
    int c_lane = ((lane & 3) << 4) | (lane >> 2);
    unsigned beg = rowstart[node], end = rowstart[node + 1];

    float sqv[RR];
    float m = -1e30f;
    #pragma unroll
    for (int r = 0; r < RR; r++) {
        sqv[r] = sq[(size_t)r * NN + node];
        m = fmaxf(m, sqv[r] + funmap(mxk_u[r]));
    }
    m = m > 0.f ? m : 0.2f * m;   // leaky is monotonic: bound survives

    float acc0 = 0.f, acc1 = 0.f, acc2 = 0.f, acc3 = 0.f, den = 0.f;
    for (unsigned c0 = beg; c0 < end; c0 += 64) {
        unsigned i = c0 + lane;
        float w = 0.f;
        unsigned rowidx = 0;
        if (i < end) {
            unsigned p = pk[i];
            unsigned r = p >> 20;
            rowidx = r * NN + (p & 0xFFFFFu);
            float a = sqv[r] + sk[rowidx];
            a = a > 0.f ? a : 0.2f * a;
            w = __expf(a - m);
            den += w;
        }
        int cnt = (int)min(64u, end - c0);
        int j = 0;
        for (; j + 3 < cnt; j += 4) {
            float    w0 = __shfl(w, j, 64),     w1 = __shfl(w, j + 1, 64);
            float    w2 = __shfl(w, j + 2, 64), w3 = __shfl(w, j + 3, 64);
            unsigned r0 = (unsigned)__shfl((int)rowidx, j, 64);
            unsigned r1 = (unsigned)__shfl((int)rowidx, j + 1, 64);
            unsigned r2 = (unsigned)__shfl((int)rowidx, j + 2, 64);
            unsigned r3 = (unsigned)__shfl((int)rowidx, j + 3, 64);
            acc0 += w0 * bf2f(xw[(size_t)r0 * 64 + lane]);
            acc1 += w1 * bf2f(xw[(size_t)r1 * 64 + lane]);
            acc2 += w2 * bf2f(xw[(size_t)r2 * 64 + lane]);
            acc3 += w3 * bf2f(xw[(size_t)r3 * 64 + lane]);
        }
        for (; j < cnt; j++) {
            float    wj = __shfl(w, j, 64);
            unsigned rj = (unsigned)__shfl((int)rowidx, j, 64);
            acc0 += wj * bf2f(xw[(size_t)rj * 64 + lane]);
        }
    }
    #pragma unroll
    for (int off = 32; off >= 1; off >>= 1)
        den += __shfl_xor(den, off, 64);

    float res = (end > beg) ? ((acc0 + acc1) + (acc2 + acc3)) / (den + 1e-16f) : 0.f;
    if constexpr (LAYER == 1) {
        res += b[c_lane];
        res = res > 0.f ? res : 0.f;
    }
    out[(size_t)node * 64 + c_lane] = res;
}

// ---------------- BatchNorm ----------------
__global__ __launch_bounds__(256)
void bn_stats(const float* __restrict__ x, float* __restrict__ stats)
{
    int c = threadIdx.x & 63;
    int w = threadIdx.x >> 6;
    float s = 0.f, s2 = 0.f;
    for (int row = blockIdx.x * 4 + w; row < NN; row += gridDim.x * 4) {
        float v = x[(size_t)row * 64 + c];
        s += v; s2 += v * v;
    }
    __shared__ float ls[4][64], ls2[4][64];
    ls[w][c] = s; ls2[w][c] = s2;
    __syncthreads();
    if (threadIdx.x < 64) {
        atomicAdd(&stats[c],      ls[0][c] + ls[1][c] + ls[2][c] + ls[3][c]);
        atomicAdd(&stats[64 + c], ls2[0][c] + ls2[1][c] + ls2[2][c] + ls2[3][c]);
    }
}

__global__ __launch_bounds__(256)
void bn_apply(float* __restrict__ x, const float* __restrict__ stats,
              const float* __restrict__ gamma, const float* __restrict__ beta)
{
    int i = blockIdx.x * 256 + threadIdx.x;
    if (i >= NN * 64) return;
    int c = i & 63;
    float mean = stats[c] * (1.f / NN);
    float var  = stats[64 + c] * (1.f / NN) - mean * mean;
    float sc   = rsqrtf(var + 1e-5f) * gamma[c];
    float v = (x[i] - mean) * sc + beta[c];
    x[i] = v > 0.f ? v : 0.01f * v;
}

// ---------------- driver ----------------
extern "C" void kernel_launch(void* const* d_in, const int* in_sizes, int n_in,
                              void* d_out, int out_size, void* d_ws, size_t ws_size,
                              hipStream_t stream)
{
    const float* x0 = (const float*)d_in[0];
    const int*   ei = (const int*)d_in[1];
    const int*   et = (const int*)d_in[2];
    const float* W1 = (const float*)d_in[3];
    const float* q1 = (const float*)d_in[4];
    const float* k1 = (const float*)d_in[5];
    const float* b1 = (const float*)d_in[6];
    const float* W2 = (const float*)d_in[7];
    const float* q2 = (const float*)d_in[8];
    const float* k2 = (const float*)d_in[9];
    const float* gamma = (const float*)d_in[11];
    const float* beta  = (const float*)d_in[12];
    const int* src = ei;
    const int* dst = ei + EE;
    float* out = (float*)d_out;

    char* base = (char*)d_ws;
    size_t off = 0;
    auto take = [&](size_t bytes) -> char* {
        char* p = base + off;
        off = (off + bytes + 255) & ~(size_t)255;
        return p;
    };
    float*    sq       = (float*)take((size_t)RR * NN * 4);
    float*    sk       = (float*)take((size_t)RR * NN * 4);
    unsigned* rowstart = (unsigned*)take((size_t)(NN + 1) * 4);
    unsigned* cnt      = (unsigned*)take((size_t)NN * 4);
    unsigned* bsum     = (unsigned*)take((size_t)NB_SCAN * 4);
    unsigned* pk       = (unsigned*)take((size_t)EE * 4);
    float*    x1       = (float*)take((size_t)NN * 64 * 4);
    float*    stats    = (float*)take(512);
    unsigned* mxk1     = (unsigned*)take(RR * 4);
    unsigned* mxk2     = (unsigned*)take(RR * 4);
    unsigned short* Wf1 = (unsigned short*)take((size_t)RR * 64 * 128 * 2);
    unsigned short* Wf2 = (unsigned short*)take((size_t)RR * 64 * 64 * 2);
    unsigned short* Sf1 = (unsigned short*)take((size_t)128 * 16 * 2);
    unsigned short* Sf2 = (unsigned short*)take((size_t)64 * 16 * 2);
    unsigned short* xw  = (unsigned short*)take((size_t)RR * NN * 64 * 2);

    const int nb_nodes = (NN + 63) / 64;
    const int nb_edges = (EE + 255) / 256;
    const int nb_agg   = NN / 4;
    const int nb_elem  = (NN * 64) / 256;
    const int nb_n256  = (NN + 255) / 256;

    wt_frag<128><<<RR, 256, 0, stream>>>(W1, Wf1);
    wt_frag<64><<<RR, 256, 0, stream>>>(W2, Wf2);
    wqk_frag<128><<<8, 256, 0, stream>>>(W1, q1, k1, Sf1);
    wqk_frag<64><<<4, 256, 0, stream>>>(W2, q2, k2, Sf2);
    init_mxk16<<<1, 64, 0, stream>>>(mxk1, mxk2);

    hipMemsetAsync(cnt, 0, (size_t)NN * 4, stream);
    csr_hist<<<nb_edges, 256, 0, stream>>>(dst, cnt);
    scan_block<<<NB_SCAN, SCAN_BS, 0, stream>>>(cnt, rowstart, bsum);
    scan_tops<<<1, 64, 0, stream>>>(bsum);
    scan_add<<<nb_n256, 256, 0, stream>>>(rowstart, bsum);
    hipMemsetAsync(cnt, 0, (size_t)NN * 4, stream);
    csr_scatter<<<nb_edges, 256, 0, stream>>>(src, dst, et, rowstart, cnt, pk);

    gemm_mfma<128><<<nb_nodes, 256, 0, stream>>>(x0, Wf1, Sf1, xw, sq, sk);
    sk_max<<<dim3(RR, 8), 256, 0, stream>>>(sk, mxk1);
    node_aggregate<1><<<nb_agg, 256, 0, stream>>>(rowstart, pk, sq, sk, mxk1, xw, b1, x1);

    gemm_mfma<64><<<nb_nodes, 256, 0, stream>>>(x1, Wf2, Sf2, xw, sq, sk);
    sk_max<<<dim3(RR, 8), 256, 0, stream>>>(sk, mxk2);
    node_aggregate<2><<<nb_agg, 256, 0, stream>>>(rowstart, pk, sq, sk, mxk2, xw, nullptr, out);

    hipMemsetAsync(stats, 0, 2 * 64 * 4, stream);
    bn_stats<<<512, 256, 0, stream>>>(out, stats);
    bn_apply<<<nb_elem, 256, 0, stream>>>(out, stats, gamma, beta);
}

// Round 9
// 490.540 us; speedup vs baseline: 7.6703x; 1.1506x over previous
//
#include <hip/hip_runtime.h>
#include <hip/hip_bf16.h>

#define NN 100000
#define EE 1600000
#define RR 8
#define NBKT 196          // ceil(NN/512) buckets of 512 nodes
#define ACHUNK 8192       // edges per partition block

typedef __attribute__((ext_vector_type(8))) short bf16x8;
typedef __attribute__((ext_vector_type(4))) float f32x4;

__device__ __forceinline__ unsigned short f2bf(float v) {
    __hip_bfloat16 h = __float2bfloat16(v);
    return *reinterpret_cast<unsigned short*>(&h);
}
__device__ __forceinline__ float bf2f(unsigned short u) {
    unsigned x = (unsigned)u << 16;
    return __uint_as_float(x);
}
__device__ __forceinline__ unsigned fmap(float a) {
    unsigned u = __float_as_uint(a);
    return (u & 0x80000000u) ? ~u : (u | 0x80000000u);
}
__device__ __forceinline__ float funmap(unsigned u) {
    return (u & 0x80000000u) ? __uint_as_float(u & 0x7FFFFFFFu) : __uint_as_float(~u);
}

// ---------- W -> MFMA B-fragment order ----------
template<int IN_DIM>
__global__ __launch_bounds__(256)
void wt_frag(const float* __restrict__ W, unsigned short* __restrict__ Wf) {
    constexpr int KSTEPS = IN_DIM / 32;
    int r = blockIdx.x;
    for (int i = threadIdx.x; i < IN_DIM * 64; i += 256) {
        int k = i >> 6, o = i & 63;
        int ks = k >> 5, quad = (k >> 3) & 3, j = k & 7;
        int tl = o >> 4, l16 = o & 15;
        int lane = quad * 16 + l16;
        size_t idx = ((((size_t)r * KSTEPS + ks) * 4 + tl) * 64 + lane) * 8 + j;
        Wf[idx] = f2bf(W[((size_t)r * IN_DIM + k) * 64 + o]);
    }
}

// ---------- packed score B-frag: col<8 -> W[col]@q, col>=8 -> W[col-8]@k ----------
template<int IN_DIM>
__global__ __launch_bounds__(256)
void wqk_frag(const float* __restrict__ W, const float* __restrict__ q,
              const float* __restrict__ k, unsigned short* __restrict__ Sf) {
    for (int i = blockIdx.x * 256 + threadIdx.x; i < IN_DIM * 16; i += gridDim.x * 256) {
        int j = i & 7, lane = (i >> 3) & 63, ks = i >> 9;
        int col = lane & 15, quad = lane >> 4;
        int kd = ks * 32 + quad * 8 + j;
        const float* v = (col < 8) ? q : k;
        int r = (col < 8) ? col : col - 8;
        float s = 0.f;
        #pragma unroll
        for (int o = 0; o < 64; o++) s += W[((size_t)r * IN_DIM + kd) * 64 + o] * v[o];
        Sf[i] = f2bf(s);
    }
}

__global__ void init_mxk16(unsigned* __restrict__ a, unsigned* __restrict__ b) {
    if (threadIdx.x < RR) { a[threadIdx.x] = fmap(-1e30f); b[threadIdx.x] = fmap(-1e30f); }
}

// per-relation max of sk (grid (RR, 8), block 256)
__global__ __launch_bounds__(256)
void sk_max(const float* __restrict__ sk, unsigned* __restrict__ mxk_u) {
    int r = blockIdx.x;
    int t = threadIdx.x;
    float m = -1e30f;
    for (int i = blockIdx.y * (NN / 8) + t; i < (blockIdx.y + 1) * (NN / 8); i += 256)
        m = fmaxf(m, sk[(size_t)r * NN + i]);
    #pragma unroll
    for (int off = 32; off >= 1; off >>= 1)
        m = fmaxf(m, __shfl_xor(m, off, 64));
    __shared__ float sm[4];
    if ((t & 63) == 0) sm[t >> 6] = m;
    __syncthreads();
    if (t == 0) {
        m = fmaxf(fmaxf(sm[0], sm[1]), fmaxf(sm[2], sm[3]));
        atomicMax(&mxk_u[r], fmap(m));
    }
}

// ---------- MFMA GEMM: xw[r,n,p] bf16 (permuted cols) = x @ W[r]; sq/sk via MFMA ----------
template<int IN_DIM>
__global__ __launch_bounds__(256)
void gemm_mfma(const float* __restrict__ x, const unsigned short* __restrict__ Wf,
               const unsigned short* __restrict__ Sf,
               unsigned short* __restrict__ xw,
               float* __restrict__ sq, float* __restrict__ sk)
{
    constexpr int KSTEPS = IN_DIM / 32;
    constexpr int NB = IN_DIM / 8;
    __shared__ unsigned short xl[64 * IN_DIM];

    const int n0 = blockIdx.x * 64;
    const int t = threadIdx.x;
    const int wave = t >> 6, lane = t & 63;
    const int quad = lane >> 4, l16 = lane & 15;

    for (int c = t; c < 64 * IN_DIM / 4; c += 256) {
        int row = c / (IN_DIM / 4), kc = (c % (IN_DIM / 4)) * 4;
        float4 v = make_float4(0.f, 0.f, 0.f, 0.f);
        int gr = n0 + row;
        if (gr < NN) v = *(const float4*)(x + (size_t)gr * IN_DIM + kc);
        ushort4 u;
        u.x = f2bf(v.x); u.y = f2bf(v.y); u.z = f2bf(v.z); u.w = f2bf(v.w);
        int b = kc >> 3;
        *(ushort4*)&xl[row * IN_DIM + ((b ^ (row & (NB - 1))) << 3) + (kc & 7)] = u;
    }
    __syncthreads();

    bf16x8 afr[KSTEPS];
    const int arow = wave * 16 + l16;
    #pragma unroll
    for (int ks = 0; ks < KSTEPS; ks++) {
        int b = ks * 4 + quad;
        afr[ks] = *(const bf16x8*)&xl[arow * IN_DIM + ((b ^ (arow & (NB - 1))) << 3)];
    }

    // ---- sq/sk for ALL relations via one MFMA chain ----
    {
        f32x4 accs = {0.f, 0.f, 0.f, 0.f};
        #pragma unroll
        for (int ks = 0; ks < KSTEPS; ks++) {
            bf16x8 sfr = *(const bf16x8*)&Sf[(ks * 64 + lane) * 8];
            accs = __builtin_amdgcn_mfma_f32_16x16x32_bf16(afr[ks], sfr, accs, 0, 0, 0);
        }
        #pragma unroll
        for (int reg = 0; reg < 4; reg++) {
            int grow = n0 + wave * 16 + quad * 4 + reg;
            if (grow < NN) {
                if (l16 < 8) sq[(size_t)l16 * NN + grow] = accs[reg];
                else         sk[(size_t)(l16 - 8) * NN + grow] = accs[reg];
            }
        }
    }

    #pragma unroll 1
    for (int r = 0; r < RR; r++) {
        bf16x8 bfr[KSTEPS][4];
        const unsigned short* Wb = Wf + (((size_t)r * KSTEPS) * 4) * 64 * 8 + lane * 8;
        #pragma unroll
        for (int ks = 0; ks < KSTEPS; ks++)
            #pragma unroll
            for (int tl = 0; tl < 4; tl++)
                bfr[ks][tl] = *(const bf16x8*)(Wb + ((ks * 4 + tl) * 64) * 8);

        f32x4 acc[4] = {{0.f,0.f,0.f,0.f},{0.f,0.f,0.f,0.f},{0.f,0.f,0.f,0.f},{0.f,0.f,0.f,0.f}};
        #pragma unroll
        for (int ks = 0; ks < KSTEPS; ks++)
            #pragma unroll
            for (int tl = 0; tl < 4; tl++)
                acc[tl] = __builtin_amdgcn_mfma_f32_16x16x32_bf16(afr[ks], bfr[ks][tl], acc[tl], 0, 0, 0);

        const size_t rbase = (size_t)r * NN;
        #pragma unroll
        for (int reg = 0; reg < 4; reg++) {
            int grow = n0 + wave * 16 + quad * 4 + reg;
            if (grow < NN) {
                ushort4 u;
                u.x = f2bf(acc[0][reg]); u.y = f2bf(acc[1][reg]);
                u.z = f2bf(acc[2][reg]); u.w = f2bf(acc[3][reg]);
                *(ushort4*)(xw + (rbase + grow) * 64 + l16 * 4) = u;
            }
        }
    }
}

// ---------------- bucketed CSR build ----------------
// bucket b = dst >> 9 (512 nodes per bucket, NBKT buckets)
__global__ __launch_bounds__(256)
void bucket_hist(const int* __restrict__ dst, unsigned* __restrict__ bcnt) {
    __shared__ unsigned h[NBKT];
    int t = threadIdx.x;
    for (int i = t; i < NBKT; i += 256) h[i] = 0;
    __syncthreads();
    int e0 = blockIdx.x * ACHUNK;
    for (int i = t; i < ACHUNK; i += 256) {
        int e = e0 + i;
        if (e < EE) atomicAdd(&h[((unsigned)dst[e]) >> 9], 1u);
    }
    __syncthreads();
    for (int i = t; i < NBKT; i += 256)
        if (h[i]) atomicAdd(&bcnt[i], h[i]);
}

__global__ void bucket_scan(const unsigned* __restrict__ bcnt, unsigned* __restrict__ bstart,
                            unsigned* __restrict__ bcur, unsigned* __restrict__ rowstart) {
    if (threadIdx.x == 0) {
        unsigned run = 0;
        for (int i = 0; i < NBKT; i++) { bstart[i] = run; bcur[i] = run; run += bcnt[i]; }
        bstart[NBKT] = run;      // == EE
        rowstart[NN] = EE;
    }
}

// partition edges into bucket-contiguous tmp regions.
// payload: (d_local 9b << 23) | (et 3b << 20) | src 17b
__global__ __launch_bounds__(256)
void part_scatter(const int* __restrict__ src, const int* __restrict__ dst,
                  const int* __restrict__ et, unsigned* __restrict__ bcur,
                  unsigned* __restrict__ tmp) {
    __shared__ unsigned h[NBKT], base[NBKT];
    int t = threadIdx.x;
    for (int i = t; i < NBKT; i += 256) h[i] = 0;
    __syncthreads();
    int e0 = blockIdx.x * ACHUNK;
    for (int i = t; i < ACHUNK; i += 256) {
        int e = e0 + i;
        if (e < EE) atomicAdd(&h[((unsigned)dst[e]) >> 9], 1u);
    }
    __syncthreads();
    for (int i = t; i < NBKT; i += 256) {
        base[i] = h[i] ? atomicAdd(&bcur[i], h[i]) : 0u;
        h[i] = 0;
    }
    __syncthreads();
    for (int i = t; i < ACHUNK; i += 256) {
        int e = e0 + i;
        if (e < EE) {
            unsigned d = (unsigned)dst[e];
            unsigned b = d >> 9;
            unsigned off = atomicAdd(&h[b], 1u);
            unsigned val = ((d & 511u) << 23) | ((unsigned)et[e] << 20) | (unsigned)src[e];
            tmp[base[b] + off] = val;
        }
    }
}

// one block per bucket: local counts -> LDS scan -> rowstart + L2-local scatter
__global__ __launch_bounds__(512)
void bucket_csr(const unsigned* __restrict__ bstart, const unsigned* __restrict__ tmp,
                unsigned* __restrict__ rowstart, unsigned* __restrict__ pk) {
    __shared__ unsigned lcnt[512], lscan[512], lrs[512];
    int b = blockIdx.x, t = threadIdx.x;
    unsigned ebeg = bstart[b], eend = bstart[b + 1];
    lcnt[t] = 0;
    __syncthreads();
    for (unsigned i = ebeg + t; i < eend; i += 512)
        atomicAdd(&lcnt[tmp[i] >> 23], 1u);
    __syncthreads();
    unsigned v = lcnt[t];
    lscan[t] = v;
    __syncthreads();
    for (int off = 1; off < 512; off <<= 1) {
        unsigned u = (t >= off) ? lscan[t - off] : 0u;
        __syncthreads();
        lscan[t] += u;
        __syncthreads();
    }
    unsigned excl = lscan[t] - v;
    lrs[t] = ebeg + excl;
    int node = b * 512 + t;
    if (node < NN) rowstart[node] = ebeg + excl;
    lcnt[t] = 0;
    __syncthreads();
    for (unsigned i = ebeg + t; i < eend; i += 512) {
        unsigned val = tmp[i];
        unsigned d = val >> 23;
        unsigned pos = lrs[d] + atomicAdd(&lcnt[d], 1u);
        pk[pos] = val & 0x7FFFFFu;
    }
}

// ---------- Fused per-node softmax + aggregate ----------
// Upper-bound max (no per-edge max pass): m = leaky(max_r(sq[r,node]+mxk[r])).
// lane's xw position = lane; its true channel = (lane&3)*16 + (lane>>2)
template<int LAYER>
__global__ __launch_bounds__(256)
void node_aggregate(const unsigned* __restrict__ rowstart, const unsigned* __restrict__ pk,
                    const float* __restrict__ sq, const float* __restrict__ sk,
                    const unsigned* __restrict__ mxk_u,
                    const unsigned short* __restrict__ xw, const float* __restrict__ b,
                    float* __restrict__ out)
{
    int node = blockIdx.x * 4 + (threadIdx.x >> 6);
    int lane = threadIdx.x & 63;
    int c_lane = ((lane & 3) << 4) | (lane >> 2);
    unsigned beg = rowstart[node], end = rowstart[node + 1];

    float sqv[RR];
    float m = -1e30f;
    #pragma unroll
    for (int r = 0; r < RR; r++) {
        sqv[r] = sq[(size_t)r * NN + node];
        m = fmaxf(m, sqv[r] + funmap(mxk_u[r]));
    }
    m = m > 0.f ? m : 0.2f * m;   // leaky is monotonic: bound survives

    float acc0 = 0.f, acc1 = 0.f, acc2 = 0.f, acc3 = 0.f, den = 0.f;
    for (unsigned c0 = beg; c0 < end; c0 += 64) {
        unsigned i = c0 + lane;
        float w = 0.f;
        unsigned rowidx = 0;
        if (i < end) {
            unsigned p = pk[i];
            unsigned r = p >> 20;
            rowidx = r * NN + (p & 0xFFFFFu);
            float a = sqv[r] + sk[rowidx];
            a = a > 0.f ? a : 0.2f * a;
            w = __expf(a - m);
            den += w;
        }
        int cnt = (int)min(64u, end - c0);
        int j = 0;
        for (; j + 3 < cnt; j += 4) {
            float    w0 = __shfl(w, j, 64),     w1 = __shfl(w, j + 1, 64);
            float    w2 = __shfl(w, j + 2, 64), w3 = __shfl(w, j + 3, 64);
            unsigned r0 = (unsigned)__shfl((int)rowidx, j, 64);
            unsigned r1 = (unsigned)__shfl((int)rowidx, j + 1, 64);
            unsigned r2 = (unsigned)__shfl((int)rowidx, j + 2, 64);
            unsigned r3 = (unsigned)__shfl((int)rowidx, j + 3, 64);
            acc0 += w0 * bf2f(xw[(size_t)r0 * 64 + lane]);
            acc1 += w1 * bf2f(xw[(size_t)r1 * 64 + lane]);
            acc2 += w2 * bf2f(xw[(size_t)r2 * 64 + lane]);
            acc3 += w3 * bf2f(xw[(size_t)r3 * 64 + lane]);
        }
        for (; j < cnt; j++) {
            float    wj = __shfl(w, j, 64);
            unsigned rj = (unsigned)__shfl((int)rowidx, j, 64);
            acc0 += wj * bf2f(xw[(size_t)rj * 64 + lane]);
        }
    }
    #pragma unroll
    for (int off = 32; off >= 1; off >>= 1)
        den += __shfl_xor(den, off, 64);

    float res = (end > beg) ? ((acc0 + acc1) + (acc2 + acc3)) / (den + 1e-16f) : 0.f;
    if constexpr (LAYER == 1) {
        res += b[c_lane];
        res = res > 0.f ? res : 0.f;
    }
    out[(size_t)node * 64 + c_lane] = res;
}

// ---------------- BatchNorm ----------------
__global__ __launch_bounds__(256)
void bn_stats(const float* __restrict__ x, float* __restrict__ stats)
{
    int c = threadIdx.x & 63;
    int w = threadIdx.x >> 6;
    float s = 0.f, s2 = 0.f;
    for (int row = blockIdx.x * 4 + w; row < NN; row += gridDim.x * 4) {
        float v = x[(size_t)row * 64 + c];
        s += v; s2 += v * v;
    }
    __shared__ float ls[4][64], ls2[4][64];
    ls[w][c] = s; ls2[w][c] = s2;
    __syncthreads();
    if (threadIdx.x < 64) {
        atomicAdd(&stats[c],      ls[0][c] + ls[1][c] + ls[2][c] + ls[3][c]);
        atomicAdd(&stats[64 + c], ls2[0][c] + ls2[1][c] + ls2[2][c] + ls2[3][c]);
    }
}

__global__ __launch_bounds__(256)
void bn_apply(float* __restrict__ x, const float* __restrict__ stats,
              const float* __restrict__ gamma, const float* __restrict__ beta)
{
    int i = blockIdx.x * 256 + threadIdx.x;
    if (i >= NN * 64) return;
    int c = i & 63;
    float mean = stats[c] * (1.f / NN);
    float var  = stats[64 + c] * (1.f / NN) - mean * mean;
    float sc   = rsqrtf(var + 1e-5f) * gamma[c];
    float v = (x[i] - mean) * sc + beta[c];
    x[i] = v > 0.f ? v : 0.01f * v;
}

// ---------------- driver ----------------
extern "C" void kernel_launch(void* const* d_in, const int* in_sizes, int n_in,
                              void* d_out, int out_size, void* d_ws, size_t ws_size,
                              hipStream_t stream)
{
    const float* x0 = (const float*)d_in[0];
    const int*   ei = (const int*)d_in[1];
    const int*   et = (const int*)d_in[2];
    const float* W1 = (const float*)d_in[3];
    const float* q1 = (const float*)d_in[4];
    const float* k1 = (const float*)d_in[5];
    const float* b1 = (const float*)d_in[6];
    const float* W2 = (const float*)d_in[7];
    const float* q2 = (const float*)d_in[8];
    const float* k2 = (const float*)d_in[9];
    const float* gamma = (const float*)d_in[11];
    const float* beta  = (const float*)d_in[12];
    const int* src = ei;
    const int* dst = ei + EE;
    float* out = (float*)d_out;

    char* base = (char*)d_ws;
    size_t off = 0;
    auto take = [&](size_t bytes) -> char* {
        char* p = base + off;
        off = (off + bytes + 255) & ~(size_t)255;
        return p;
    };
    float*    sq       = (float*)take((size_t)RR * NN * 4);
    float*    sk       = (float*)take((size_t)RR * NN * 4);
    unsigned* rowstart = (unsigned*)take((size_t)(NN + 1) * 4);
    unsigned* bcnt     = (unsigned*)take((size_t)NBKT * 4);
    unsigned* bstart   = (unsigned*)take((size_t)(NBKT + 1) * 4);
    unsigned* bcur     = (unsigned*)take((size_t)NBKT * 4);
    unsigned* tmp      = (unsigned*)take((size_t)EE * 4);
    unsigned* pk       = (unsigned*)take((size_t)EE * 4);
    float*    x1       = (float*)take((size_t)NN * 64 * 4);
    float*    stats    = (float*)take(512);
    unsigned* mxk1     = (unsigned*)take(RR * 4);
    unsigned* mxk2     = (unsigned*)take(RR * 4);
    unsigned short* Wf1 = (unsigned short*)take((size_t)RR * 64 * 128 * 2);
    unsigned short* Wf2 = (unsigned short*)take((size_t)RR * 64 * 64 * 2);
    unsigned short* Sf1 = (unsigned short*)take((size_t)128 * 16 * 2);
    unsigned short* Sf2 = (unsigned short*)take((size_t)64 * 16 * 2);
    unsigned short* xw  = (unsigned short*)take((size_t)RR * NN * 64 * 2);

    const int nb_nodes = (NN + 63) / 64;
    const int nb_part  = (EE + ACHUNK - 1) / ACHUNK;   // 196
    const int nb_agg   = NN / 4;
    const int nb_elem  = (NN * 64) / 256;

    wt_frag<128><<<RR, 256, 0, stream>>>(W1, Wf1);
    wt_frag<64><<<RR, 256, 0, stream>>>(W2, Wf2);
    wqk_frag<128><<<8, 256, 0, stream>>>(W1, q1, k1, Sf1);
    wqk_frag<64><<<4, 256, 0, stream>>>(W2, q2, k2, Sf2);
    init_mxk16<<<1, 64, 0, stream>>>(mxk1, mxk2);

    // ---- bucketed CSR build ----
    hipMemsetAsync(bcnt, 0, (size_t)NBKT * 4, stream);
    bucket_hist<<<nb_part, 256, 0, stream>>>(dst, bcnt);
    bucket_scan<<<1, 64, 0, stream>>>(bcnt, bstart, bcur, rowstart);
    part_scatter<<<nb_part, 256, 0, stream>>>(src, dst, et, bcur, tmp);
    bucket_csr<<<NBKT, 512, 0, stream>>>(bstart, tmp, rowstart, pk);

    gemm_mfma<128><<<nb_nodes, 256, 0, stream>>>(x0, Wf1, Sf1, xw, sq, sk);
    sk_max<<<dim3(RR, 8), 256, 0, stream>>>(sk, mxk1);
    node_aggregate<1><<<nb_agg, 256, 0, stream>>>(rowstart, pk, sq, sk, mxk1, xw, b1, x1);

    gemm_mfma<64><<<nb_nodes, 256, 0, stream>>>(x1, Wf2, Sf2, xw, sq, sk);
    sk_max<<<dim3(RR, 8), 256, 0, stream>>>(sk, mxk2);
    node_aggregate<2><<<nb_agg, 256, 0, stream>>>(rowstart, pk, sq, sk, mxk2, xw, nullptr, out);

    hipMemsetAsync(stats, 0, 2 * 64 * 4, stream);
    bn_stats<<<512, 256, 0, stream>>>(out, stats);
    bn_apply<<<nb_elem, 256, 0, stream>>>(out, stats, gamma, beta);
}

// Round 10
// 486.897 us; speedup vs baseline: 7.7277x; 1.0075x over previous
//
#include <hip/hip_runtime.h>
#include <hip/hip_bf16.h>

#define NN 100000
#define EE 1600000
#define RR 8
#define NBKT 196          // ceil(NN/512) buckets of 512 nodes
#define ACHUNK 8192       // edges per partition block

typedef __attribute__((ext_vector_type(8))) short bf16x8;
typedef __attribute__((ext_vector_type(4))) float f32x4;

__device__ __forceinline__ unsigned short f2bf(float v) {
    __hip_bfloat16 h = __float2bfloat16(v);
    return *reinterpret_cast<unsigned short*>(&h);
}
__device__ __forceinline__ float bf2f(unsigned short u) {
    unsigned x = (unsigned)u << 16;
    return __uint_as_float(x);
}
__device__ __forceinline__ unsigned fmap(float a) {
    unsigned u = __float_as_uint(a);
    return (u & 0x80000000u) ? ~u : (u | 0x80000000u);
}
__device__ __forceinline__ float funmap(unsigned u) {
    return (u & 0x80000000u) ? __uint_as_float(u & 0x7FFFFFFFu) : __uint_as_float(~u);
}

// ---------- W -> MFMA B-fragment order ----------
template<int IN_DIM>
__global__ __launch_bounds__(256)
void wt_frag(const float* __restrict__ W, unsigned short* __restrict__ Wf) {
    constexpr int KSTEPS = IN_DIM / 32;
    int r = blockIdx.x;
    for (int i = threadIdx.x; i < IN_DIM * 64; i += 256) {
        int k = i >> 6, o = i & 63;
        int ks = k >> 5, quad = (k >> 3) & 3, j = k & 7;
        int tl = o >> 4, l16 = o & 15;
        int lane = quad * 16 + l16;
        size_t idx = ((((size_t)r * KSTEPS + ks) * 4 + tl) * 64 + lane) * 8 + j;
        Wf[idx] = f2bf(W[((size_t)r * IN_DIM + k) * 64 + o]);
    }
}

// ---------- packed score B-frag: col<8 -> W[col]@q, col>=8 -> W[col-8]@k ----------
template<int IN_DIM>
__global__ __launch_bounds__(256)
void wqk_frag(const float* __restrict__ W, const float* __restrict__ q,
              const float* __restrict__ k, unsigned short* __restrict__ Sf) {
    for (int i = blockIdx.x * 256 + threadIdx.x; i < IN_DIM * 16; i += gridDim.x * 256) {
        int j = i & 7, lane = (i >> 3) & 63, ks = i >> 9;
        int col = lane & 15, quad = lane >> 4;
        int kd = ks * 32 + quad * 8 + j;
        const float* v = (col < 8) ? q : k;
        int r = (col < 8) ? col : col - 8;
        float s = 0.f;
        #pragma unroll
        for (int o = 0; o < 64; o++) s += W[((size_t)r * IN_DIM + kd) * 64 + o] * v[o];
        Sf[i] = f2bf(s);
    }
}

__global__ void init_mxk16(unsigned* __restrict__ a, unsigned* __restrict__ b) {
    if (threadIdx.x < RR) { a[threadIdx.x] = fmap(-1e30f); b[threadIdx.x] = fmap(-1e30f); }
}

// per-relation max of sk (grid (RR, 8), block 256)
__global__ __launch_bounds__(256)
void sk_max(const float* __restrict__ sk, unsigned* __restrict__ mxk_u) {
    int r = blockIdx.x;
    int t = threadIdx.x;
    float m = -1e30f;
    for (int i = blockIdx.y * (NN / 8) + t; i < (blockIdx.y + 1) * (NN / 8); i += 256)
        m = fmaxf(m, sk[(size_t)r * NN + i]);
    #pragma unroll
    for (int off = 32; off >= 1; off >>= 1)
        m = fmaxf(m, __shfl_xor(m, off, 64));
    __shared__ float sm[4];
    if ((t & 63) == 0) sm[t >> 6] = m;
    __syncthreads();
    if (t == 0) {
        m = fmaxf(fmaxf(sm[0], sm[1]), fmaxf(sm[2], sm[3]));
        atomicMax(&mxk_u[r], fmap(m));
    }
}

// ---------- MFMA GEMM: xw[r,n,p] bf16 (permuted cols) = x @ W[r]; sq/sk via MFMA ----------
template<int IN_DIM>
__global__ __launch_bounds__(256)
void gemm_mfma(const float* __restrict__ x, const unsigned short* __restrict__ Wf,
               const unsigned short* __restrict__ Sf,
               unsigned short* __restrict__ xw,
               float* __restrict__ sq, float* __restrict__ sk)
{
    constexpr int KSTEPS = IN_DIM / 32;
    constexpr int NB = IN_DIM / 8;
    __shared__ unsigned short xl[64 * IN_DIM];

    const int n0 = blockIdx.x * 64;
    const int t = threadIdx.x;
    const int wave = t >> 6, lane = t & 63;
    const int quad = lane >> 4, l16 = lane & 15;

    for (int c = t; c < 64 * IN_DIM / 4; c += 256) {
        int row = c / (IN_DIM / 4), kc = (c % (IN_DIM / 4)) * 4;
        float4 v = make_float4(0.f, 0.f, 0.f, 0.f);
        int gr = n0 + row;
        if (gr < NN) v = *(const float4*)(x + (size_t)gr * IN_DIM + kc);
        ushort4 u;
        u.x = f2bf(v.x); u.y = f2bf(v.y); u.z = f2bf(v.z); u.w = f2bf(v.w);
        int b = kc >> 3;
        *(ushort4*)&xl[row * IN_DIM + ((b ^ (row & (NB - 1))) << 3) + (kc & 7)] = u;
    }
    __syncthreads();

    bf16x8 afr[KSTEPS];
    const int arow = wave * 16 + l16;
    #pragma unroll
    for (int ks = 0; ks < KSTEPS; ks++) {
        int b = ks * 4 + quad;
        afr[ks] = *(const bf16x8*)&xl[arow * IN_DIM + ((b ^ (arow & (NB - 1))) << 3)];
    }

    // ---- sq/sk for ALL relations via one MFMA chain ----
    {
        f32x4 accs = {0.f, 0.f, 0.f, 0.f};
        #pragma unroll
        for (int ks = 0; ks < KSTEPS; ks++) {
            bf16x8 sfr = *(const bf16x8*)&Sf[(ks * 64 + lane) * 8];
            accs = __builtin_amdgcn_mfma_f32_16x16x32_bf16(afr[ks], sfr, accs, 0, 0, 0);
        }
        #pragma unroll
        for (int reg = 0; reg < 4; reg++) {
            int grow = n0 + wave * 16 + quad * 4 + reg;
            if (grow < NN) {
                if (l16 < 8) sq[(size_t)l16 * NN + grow] = accs[reg];
                else         sk[(size_t)(l16 - 8) * NN + grow] = accs[reg];
            }
        }
    }

    #pragma unroll 1
    for (int r = 0; r < RR; r++) {
        bf16x8 bfr[KSTEPS][4];
        const unsigned short* Wb = Wf + (((size_t)r * KSTEPS) * 4) * 64 * 8 + lane * 8;
        #pragma unroll
        for (int ks = 0; ks < KSTEPS; ks++)
            #pragma unroll
            for (int tl = 0; tl < 4; tl++)
                bfr[ks][tl] = *(const bf16x8*)(Wb + ((ks * 4 + tl) * 64) * 8);

        f32x4 acc[4] = {{0.f,0.f,0.f,0.f},{0.f,0.f,0.f,0.f},{0.f,0.f,0.f,0.f},{0.f,0.f,0.f,0.f}};
        #pragma unroll
        for (int ks = 0; ks < KSTEPS; ks++)
            #pragma unroll
            for (int tl = 0; tl < 4; tl++)
                acc[tl] = __builtin_amdgcn_mfma_f32_16x16x32_bf16(afr[ks], bfr[ks][tl], acc[tl], 0, 0, 0);

        const size_t rbase = (size_t)r * NN;
        #pragma unroll
        for (int reg = 0; reg < 4; reg++) {
            int grow = n0 + wave * 16 + quad * 4 + reg;
            if (grow < NN) {
                ushort4 u;
                u.x = f2bf(acc[0][reg]); u.y = f2bf(acc[1][reg]);
                u.z = f2bf(acc[2][reg]); u.w = f2bf(acc[3][reg]);
                *(ushort4*)(xw + (rbase + grow) * 64 + l16 * 4) = u;
            }
        }
    }
}

// ---------------- bucketed CSR build ----------------
__global__ __launch_bounds__(256)
void bucket_hist(const int* __restrict__ dst, unsigned* __restrict__ bcnt) {
    __shared__ unsigned h[NBKT];
    int t = threadIdx.x;
    for (int i = t; i < NBKT; i += 256) h[i] = 0;
    __syncthreads();
    int e0 = blockIdx.x * ACHUNK;
    for (int i = t; i < ACHUNK; i += 256) {
        int e = e0 + i;
        if (e < EE) atomicAdd(&h[((unsigned)dst[e]) >> 9], 1u);
    }
    __syncthreads();
    for (int i = t; i < NBKT; i += 256)
        if (h[i]) atomicAdd(&bcnt[i], h[i]);
}

__global__ void bucket_scan(const unsigned* __restrict__ bcnt, unsigned* __restrict__ bstart,
                            unsigned* __restrict__ bcur, unsigned* __restrict__ rowstart) {
    if (threadIdx.x == 0) {
        unsigned run = 0;
        for (int i = 0; i < NBKT; i++) { bstart[i] = run; bcur[i] = run; run += bcnt[i]; }
        bstart[NBKT] = run;
        rowstart[NN] = EE;
    }
}

__global__ __launch_bounds__(256)
void part_scatter(const int* __restrict__ src, const int* __restrict__ dst,
                  const int* __restrict__ et, unsigned* __restrict__ bcur,
                  unsigned* __restrict__ tmp) {
    __shared__ unsigned h[NBKT], base[NBKT];
    int t = threadIdx.x;
    for (int i = t; i < NBKT; i += 256) h[i] = 0;
    __syncthreads();
    int e0 = blockIdx.x * ACHUNK;
    for (int i = t; i < ACHUNK; i += 256) {
        int e = e0 + i;
        if (e < EE) atomicAdd(&h[((unsigned)dst[e]) >> 9], 1u);
    }
    __syncthreads();
    for (int i = t; i < NBKT; i += 256) {
        base[i] = h[i] ? atomicAdd(&bcur[i], h[i]) : 0u;
        h[i] = 0;
    }
    __syncthreads();
    for (int i = t; i < ACHUNK; i += 256) {
        int e = e0 + i;
        if (e < EE) {
            unsigned d = (unsigned)dst[e];
            unsigned b = d >> 9;
            unsigned off = atomicAdd(&h[b], 1u);
            unsigned val = ((d & 511u) << 23) | ((unsigned)et[e] << 20) | (unsigned)src[e];
            tmp[base[b] + off] = val;
        }
    }
}

__global__ __launch_bounds__(512)
void bucket_csr(const unsigned* __restrict__ bstart, const unsigned* __restrict__ tmp,
                unsigned* __restrict__ rowstart, unsigned* __restrict__ pk) {
    __shared__ unsigned lcnt[512], lscan[512], lrs[512];
    int b = blockIdx.x, t = threadIdx.x;
    unsigned ebeg = bstart[b], eend = bstart[b + 1];
    lcnt[t] = 0;
    __syncthreads();
    for (unsigned i = ebeg + t; i < eend; i += 512)
        atomicAdd(&lcnt[tmp[i] >> 23], 1u);
    __syncthreads();
    unsigned v = lcnt[t];
    lscan[t] = v;
    __syncthreads();
    for (int off = 1; off < 512; off <<= 1) {
        unsigned u = (t >= off) ? lscan[t - off] : 0u;
        __syncthreads();
        lscan[t] += u;
        __syncthreads();
    }
    unsigned excl = lscan[t] - v;
    lrs[t] = ebeg + excl;
    int node = b * 512 + t;
    if (node < NN) rowstart[node] = ebeg + excl;
    lcnt[t] = 0;
    __syncthreads();
    for (unsigned i = ebeg + t; i < eend; i += 512) {
        unsigned val = tmp[i];
        unsigned d = val >> 23;
        unsigned pos = lrs[d] + atomicAdd(&lcnt[d], 1u);
        pk[pos] = val & 0x7FFFFFu;
    }
}

// ---------- Fused per-node softmax + aggregate, 4-edges-per-iter gather ----------
// lane = (g = lane>>4, c16 = lane&15); lane loads ushort4 at xw row positions
// c16*4..+3 of edge j+g. Position p=c16*4+k holds true channel k*16+c16, so
// after shfl_xor(16/32) reduction lane writes channel g*16+c16.
template<int LAYER>
__global__ __launch_bounds__(256)
void node_aggregate(const unsigned* __restrict__ rowstart, const unsigned* __restrict__ pk,
                    const float* __restrict__ sq, const float* __restrict__ sk,
                    const unsigned* __restrict__ mxk_u,
                    const unsigned short* __restrict__ xw, const float* __restrict__ b,
                    float* __restrict__ out)
{
    int node = blockIdx.x * 4 + (threadIdx.x >> 6);
    int lane = threadIdx.x & 63;
    int g = lane >> 4, c16 = lane & 15;
    unsigned beg = rowstart[node], end = rowstart[node + 1];

    float sqv[RR];
    float m = -1e30f;
    #pragma unroll
    for (int r = 0; r < RR; r++) {
        sqv[r] = sq[(size_t)r * NN + node];
        m = fmaxf(m, sqv[r] + funmap(mxk_u[r]));
    }
    m = m > 0.f ? m : 0.2f * m;   // leaky is monotonic: upper bound survives

    float a0 = 0.f, a1 = 0.f, a2 = 0.f, a3 = 0.f, den = 0.f;
    for (unsigned c0 = beg; c0 < end; c0 += 64) {
        unsigned i = c0 + lane;
        float w = 0.f;
        unsigned rowidx = 0;
        if (i < end) {
            unsigned p = pk[i];
            unsigned r = p >> 20;
            rowidx = r * NN + (p & 0xFFFFFu);
            float a = sqv[r] + sk[rowidx];
            a = a > 0.f ? a : 0.2f * a;
            w = __expf(a - m);
            den += w;
        }
        int cnt4 = ((int)min(64u, end - c0) + 3) & ~3;   // pad lanes have w=0
        for (int j = 0; j < cnt4; j += 4) {
            float    wj = __shfl(w, j + g, 64);
            unsigned rj = (unsigned)__shfl((int)rowidx, j + g, 64);
            ushort4 v4 = *(const ushort4*)(xw + (size_t)rj * 64 + c16 * 4);
            a0 += wj * bf2f(v4.x);
            a1 += wj * bf2f(v4.y);
            a2 += wj * bf2f(v4.z);
            a3 += wj * bf2f(v4.w);
        }
    }
    #pragma unroll
    for (int off = 32; off >= 1; off >>= 1)
        den += __shfl_xor(den, off, 64);
    // combine the 4 edge-subgroups: lanes L, L^16, L^32, L^48 hold same channels
    a0 += __shfl_xor(a0, 16, 64); a0 += __shfl_xor(a0, 32, 64);
    a1 += __shfl_xor(a1, 16, 64); a1 += __shfl_xor(a1, 32, 64);
    a2 += __shfl_xor(a2, 16, 64); a2 += __shfl_xor(a2, 32, 64);
    a3 += __shfl_xor(a3, 16, 64); a3 += __shfl_xor(a3, 32, 64);

    float accg = (g == 0) ? a0 : (g == 1) ? a1 : (g == 2) ? a2 : a3;
    float res = (end > beg) ? accg / (den + 1e-16f) : 0.f;
    int c = g * 16 + c16;
    if constexpr (LAYER == 1) {
        res += b[c];
        res = res > 0.f ? res : 0.f;
    }
    out[(size_t)node * 64 + c] = res;
}

// ---------------- BatchNorm ----------------
__global__ __launch_bounds__(256)
void bn_stats(const float* __restrict__ x, float* __restrict__ stats)
{
    int c = threadIdx.x & 63;
    int w = threadIdx.x >> 6;
    float s = 0.f, s2 = 0.f;
    for (int row = blockIdx.x * 4 + w; row < NN; row += gridDim.x * 4) {
        float v = x[(size_t)row * 64 + c];
        s += v; s2 += v * v;
    }
    __shared__ float ls[4][64], ls2[4][64];
    ls[w][c] = s; ls2[w][c] = s2;
    __syncthreads();
    if (threadIdx.x < 64) {
        atomicAdd(&stats[c],      ls[0][c] + ls[1][c] + ls[2][c] + ls[3][c]);
        atomicAdd(&stats[64 + c], ls2[0][c] + ls2[1][c] + ls2[2][c] + ls2[3][c]);
    }
}

__global__ __launch_bounds__(256)
void bn_apply(float* __restrict__ x, const float* __restrict__ stats,
              const float* __restrict__ gamma, const float* __restrict__ beta)
{
    int i = blockIdx.x * 256 + threadIdx.x;
    if (i >= NN * 64) return;
    int c = i & 63;
    float mean = stats[c] * (1.f / NN);
    float var  = stats[64 + c] * (1.f / NN) - mean * mean;
    float sc   = rsqrtf(var + 1e-5f) * gamma[c];
    float v = (x[i] - mean) * sc + beta[c];
    x[i] = v > 0.f ? v : 0.01f * v;
}

// ---------------- driver ----------------
extern "C" void kernel_launch(void* const* d_in, const int* in_sizes, int n_in,
                              void* d_out, int out_size, void* d_ws, size_t ws_size,
                              hipStream_t stream)
{
    const float* x0 = (const float*)d_in[0];
    const int*   ei = (const int*)d_in[1];
    const int*   et = (const int*)d_in[2];
    const float* W1 = (const float*)d_in[3];
    const float* q1 = (const float*)d_in[4];
    const float* k1 = (const float*)d_in[5];
    const float* b1 = (const float*)d_in[6];
    const float* W2 = (const float*)d_in[7];
    const float* q2 = (const float*)d_in[8];
    const float* k2 = (const float*)d_in[9];
    const float* gamma = (const float*)d_in[11];
    const float* beta  = (const float*)d_in[12];
    const int* src = ei;
    const int* dst = ei + EE;
    float* out = (float*)d_out;

    char* base = (char*)d_ws;
    size_t off = 0;
    auto take = [&](size_t bytes) -> char* {
        char* p = base + off;
        off = (off + bytes + 255) & ~(size_t)255;
        return p;
    };
    float*    sq       = (float*)take((size_t)RR * NN * 4);
    float*    sk       = (float*)take((size_t)RR * NN * 4);
    unsigned* rowstart = (unsigned*)take((size_t)(NN + 1) * 4);
    unsigned* bcnt     = (unsigned*)take((size_t)NBKT * 4);
    unsigned* bstart   = (unsigned*)take((size_t)(NBKT + 1) * 4);
    unsigned* bcur     = (unsigned*)take((size_t)NBKT * 4);
    unsigned* tmp      = (unsigned*)take((size_t)EE * 4);
    unsigned* pk       = (unsigned*)take((size_t)EE * 4);
    float*    x1       = (float*)take((size_t)NN * 64 * 4);
    float*    stats    = (float*)take(512);
    unsigned* mxk1     = (unsigned*)take(RR * 4);
    unsigned* mxk2     = (unsigned*)take(RR * 4);
    unsigned short* Wf1 = (unsigned short*)take((size_t)RR * 64 * 128 * 2);
    unsigned short* Wf2 = (unsigned short*)take((size_t)RR * 64 * 64 * 2);
    unsigned short* Sf1 = (unsigned short*)take((size_t)128 * 16 * 2);
    unsigned short* Sf2 = (unsigned short*)take((size_t)64 * 16 * 2);
    unsigned short* xw  = (unsigned short*)take((size_t)RR * NN * 64 * 2);

    const int nb_nodes = (NN + 63) / 64;
    const int nb_part  = (EE + ACHUNK - 1) / ACHUNK;   // 196
    const int nb_agg   = NN / 4;
    const int nb_elem  = (NN * 64) / 256;

    wt_frag<128><<<RR, 256, 0, stream>>>(W1, Wf1);
    wt_frag<64><<<RR, 256, 0, stream>>>(W2, Wf2);
    wqk_frag<128><<<8, 256, 0, stream>>>(W1, q1, k1, Sf1);
    wqk_frag<64><<<4, 256, 0, stream>>>(W2, q2, k2, Sf2);
    init_mxk16<<<1, 64, 0, stream>>>(mxk1, mxk2);

    hipMemsetAsync(bcnt, 0, (size_t)NBKT * 4, stream);
    bucket_hist<<<nb_part, 256, 0, stream>>>(dst, bcnt);
    bucket_scan<<<1, 64, 0, stream>>>(bcnt, bstart, bcur, rowstart);
    part_scatter<<<nb_part, 256, 0, stream>>>(src, dst, et, bcur, tmp);
    bucket_csr<<<NBKT, 512, 0, stream>>>(bstart, tmp, rowstart, pk);

    gemm_mfma<128><<<nb_nodes, 256, 0, stream>>>(x0, Wf1, Sf1, xw, sq, sk);
    sk_max<<<dim3(RR, 8), 256, 0, stream>>>(sk, mxk1);
    node_aggregate<1><<<nb_agg, 256, 0, stream>>>(rowstart, pk, sq, sk, mxk1, xw, b1, x1);

    gemm_mfma<64><<<nb_nodes, 256, 0, stream>>>(x1, Wf2, Sf2, xw, sq, sk);
    sk_max<<<dim3(RR, 8), 256, 0, stream>>>(sk, mxk2);
    node_aggregate<2><<<nb_agg, 256, 0, stream>>>(rowstart, pk, sq, sk, mxk2, xw, nullptr, out);

    hipMemsetAsync(stats, 0, 2 * 64 * 4, stream);
    bn_stats<<<512, 256, 0, stream>>>(out, stats);
    bn_apply<<<nb_elem, 256, 0, stream>>>(out, stats, gamma, beta);
}